// Round 2
// baseline (2201.136 us; speedup 1.0000x reference)
//
#include <hip/hip_runtime.h>
#include <hip/hip_bf16.h>
#include <math.h>

#define B_ 2
#define T_ 2048
#define C_ 1024
#define H_ 16
#define HS_ 64
#define N_ROWS (B_*T_)   // 4096

// ---------------- LayerNorm: one block per row ----------------
__global__ __launch_bounds__(256) void ln_kernel(
    const float* __restrict__ x, const float* __restrict__ g,
    const float* __restrict__ b, float* __restrict__ out)
{
  const int row = blockIdx.x;
  const int tid = threadIdx.x;
  const float* xr = x + (size_t)row * C_;
  float4 xv = *reinterpret_cast<const float4*>(xr + tid * 4);
  float s  = xv.x + xv.y + xv.z + xv.w;
  float ss = xv.x*xv.x + xv.y*xv.y + xv.z*xv.z + xv.w*xv.w;
  #pragma unroll
  for (int off = 32; off > 0; off >>= 1) {
    s  += __shfl_down(s, off, 64);
    ss += __shfl_down(ss, off, 64);
  }
  __shared__ float rs[4], rss[4];
  __shared__ float smu, srstd;
  if ((tid & 63) == 0) { rs[tid >> 6] = s; rss[tid >> 6] = ss; }
  __syncthreads();
  if (tid == 0) {
    float S  = rs[0] + rs[1] + rs[2] + rs[3];
    float SS = rss[0] + rss[1] + rss[2] + rss[3];
    float mu  = S * (1.0f / C_);
    float var = SS * (1.0f / C_) - mu * mu;
    smu = mu; srstd = rsqrtf(var + 1e-5f);
  }
  __syncthreads();
  const float mu = smu, rstd = srstd;
  float4 gv = *reinterpret_cast<const float4*>(g + tid * 4);
  float4 bv = *reinterpret_cast<const float4*>(b + tid * 4);
  float4 ov;
  ov.x = (xv.x - mu) * rstd * gv.x + bv.x;
  ov.y = (xv.y - mu) * rstd * gv.y + bv.y;
  ov.z = (xv.z - mu) * rstd * gv.z + bv.z;
  ov.w = (xv.w - mu) * rstd * gv.w + bv.w;
  *reinterpret_cast<float4*>(out + (size_t)row * C_ + tid * 4) = ov;
}

// ---------------- Generic fp32 tiled GEMM ----------------
// C[M,N] = A[M,K] @ B + (bias) (+relu) (+res). 64x64 tile, 256 thr, 4x4/thr.
// BMODE 0: B row-major [K,N].  BMODE 1: B is [H, K, 64] head blocks; logical
// col n -> B[(n>>6)*K*64 + k*64 + (n&63)]  (for Wq/Wk/Wv with layout [H,C,HS]).
template<int BMODE, bool RELU, bool HASB, bool HASRES>
__global__ __launch_bounds__(256) void gemm_kernel(
    const float* __restrict__ A, const float* __restrict__ Bm,
    const float* __restrict__ bias, const float* __restrict__ res,
    float* __restrict__ Cout, int M, int N, int K)
{
  __shared__ __align__(16) float As[16][64];   // [kk][m]
  __shared__ __align__(16) float Bs[16][64];   // [kk][n]
  const int tid = threadIdx.x;
  const int tr = tid >> 4, tc = tid & 15;
  const int m0 = blockIdx.x * 64, n0 = blockIdx.y * 64;
  const int lm = tid >> 2;            // A-load row  0..63
  const int lk = (tid & 3) * 4;       // A-load kk   0,4,8,12
  const int bk = tid >> 4;            // B-load kk   0..15
  const int bn = (tid & 15) * 4;      // B-load n

  float acc[4][4] = {};

  for (int k0 = 0; k0 < K; k0 += 16) {
    float4 av = *reinterpret_cast<const float4*>(&A[(size_t)(m0 + lm) * K + k0 + lk]);
    As[lk + 0][lm] = av.x; As[lk + 1][lm] = av.y;
    As[lk + 2][lm] = av.z; As[lk + 3][lm] = av.w;
    const float* bp;
    if (BMODE == 0) {
      bp = &Bm[(size_t)(k0 + bk) * N + n0 + bn];
    } else {
      int gn = n0 + bn;
      bp = &Bm[(size_t)(gn >> 6) * ((size_t)K * 64) + (size_t)(k0 + bk) * 64 + (gn & 63)];
    }
    *reinterpret_cast<float4*>(&Bs[bk][bn]) = *reinterpret_cast<const float4*>(bp);
    __syncthreads();
    #pragma unroll
    for (int kk = 0; kk < 16; ++kk) {
      float4 a = *reinterpret_cast<const float4*>(&As[kk][tr * 4]);
      float4 b = *reinterpret_cast<const float4*>(&Bs[kk][tc * 4]);
      float aa[4] = {a.x, a.y, a.z, a.w};
      float bb[4] = {b.x, b.y, b.z, b.w};
      #pragma unroll
      for (int i = 0; i < 4; ++i)
        #pragma unroll
        for (int j = 0; j < 4; ++j)
          acc[i][j] = fmaf(aa[i], bb[j], acc[i][j]);
    }
    __syncthreads();
  }

  #pragma unroll
  for (int i = 0; i < 4; ++i) {
    const int row = m0 + tr * 4 + i;
    #pragma unroll
    for (int j = 0; j < 4; ++j) {
      const int col = n0 + tc * 4 + j;
      float v = acc[i][j];
      if (HASB)  v += bias[col];
      if (RELU)  v = v > 0.0f ? v : 0.0f;
      if (HASRES) v += res[(size_t)row * N + col];
      Cout[(size_t)row * N + col] = v;
    }
  }
}

// ---------------- Flash-style causal attention ----------------
// q,k,v in [B,T,H*HS] row-major. One block per (q-tile of 64, b*H+h).
__global__ __launch_bounds__(256) void attn_kernel(
    const float* __restrict__ q, const float* __restrict__ k,
    const float* __restrict__ v, float* __restrict__ out)
{
  const int qt = blockIdx.x;
  const int bh = blockIdx.y;
  const int b  = bh >> 4;       // / H_
  const int h  = bh & 15;       // % H_
  const int tid = threadIdx.x;
  const int tr = tid >> 4, tc = tid & 15;
  const int t0 = qt * 64;

  __shared__ __align__(16) float sQt[64][68];  // [d][qrow]
  __shared__ __align__(16) float sKt[64][68];  // [d][srow]
  __shared__ __align__(16) float sV [64][68];  // [srow][d]
  __shared__ __align__(16) float sP [64][68];  // [qrow][srow] scores->probs
  __shared__ float mrow[64], lrow[64], arow[64];

  // Load Q tile (transposed to [d][row])
  {
    const int r  = tid >> 2;            // 0..63
    const int c0 = (tid & 3) * 16;      // 0,16,32,48
    const float* src = q + ((size_t)(b * T_ + t0 + r) * C_) + h * HS_ + c0;
    #pragma unroll
    for (int u = 0; u < 4; ++u) {
      float4 t = *reinterpret_cast<const float4*>(src + u * 4);
      sQt[c0 + u*4 + 0][r] = t.x;
      sQt[c0 + u*4 + 1][r] = t.y;
      sQt[c0 + u*4 + 2][r] = t.z;
      sQt[c0 + u*4 + 3][r] = t.w;
    }
  }
  if (tid < 64) { mrow[tid] = -3.0e38f; lrow[tid] = 0.0f; }

  float o[4][4] = {};

  for (int ks = 0; ks <= qt; ++ks) {
    __syncthreads();   // protect sKt/sV/sP from previous iteration; publish Q/m on first
    // Load K (transposed) and V tiles
    {
      const int r  = tid >> 2;
      const int c0 = (tid & 3) * 16;
      const float* ksrc = k + ((size_t)(b * T_ + ks * 64 + r) * C_) + h * HS_ + c0;
      const float* vsrc = v + ((size_t)(b * T_ + ks * 64 + r) * C_) + h * HS_ + c0;
      #pragma unroll
      for (int u = 0; u < 4; ++u) {
        float4 t = *reinterpret_cast<const float4*>(ksrc + u * 4);
        sKt[c0 + u*4 + 0][r] = t.x;
        sKt[c0 + u*4 + 1][r] = t.y;
        sKt[c0 + u*4 + 2][r] = t.z;
        sKt[c0 + u*4 + 3][r] = t.w;
        *reinterpret_cast<float4*>(&sV[r][c0 + u*4]) =
            *reinterpret_cast<const float4*>(vsrc + u * 4);
      }
    }
    __syncthreads();

    // S = Q K^T
    float sacc[4][4] = {};
    #pragma unroll 16
    for (int d = 0; d < 64; ++d) {
      float4 a  = *reinterpret_cast<const float4*>(&sQt[d][tr * 4]);
      float4 bb = *reinterpret_cast<const float4*>(&sKt[d][tc * 4]);
      float aa[4] = {a.x, a.y, a.z, a.w};
      float bv[4] = {bb.x, bb.y, bb.z, bb.w};
      #pragma unroll
      for (int i = 0; i < 4; ++i)
        #pragma unroll
        for (int j = 0; j < 4; ++j)
          sacc[i][j] = fmaf(aa[i], bv[j], sacc[i][j]);
    }
    const float scale = 0.03125f;  // C^-0.5 = 1/32
    #pragma unroll
    for (int i = 0; i < 4; ++i) {
      #pragma unroll
      for (int j = 0; j < 4; ++j) {
        if (ks == qt) {
          const int rg = t0 + tr * 4 + i;
          const int cg = ks * 64 + tc * 4 + j;
          sacc[i][j] = (cg <= rg) ? sacc[i][j] * scale : -3.0e38f;
        } else {
          sacc[i][j] *= scale;
        }
      }
      float4 w = make_float4(sacc[i][0], sacc[i][1], sacc[i][2], sacc[i][3]);
      *reinterpret_cast<float4*>(&sP[tr * 4 + i][tc * 4]) = w;
    }
    __syncthreads();

    // Online softmax row pass (64 rows by threads 0..63)
    if (tid < 64) {
      float m_old = mrow[tid];
      float m = m_old;
      float* pr = sP[tid];
      for (int j = 0; j < 64; ++j) m = fmaxf(m, pr[j]);
      float sum = 0.0f;
      for (int j = 0; j < 64; ++j) {
        float e = __expf(pr[j] - m);
        pr[j] = e;
        sum += e;
      }
      float alpha = __expf(m_old - m);
      lrow[tid] = lrow[tid] * alpha + sum;
      mrow[tid] = m;
      arow[tid] = alpha;
    }
    __syncthreads();

    // Rescale accumulator and O += P @ V
    float al[4];
    #pragma unroll
    for (int i = 0; i < 4; ++i) al[i] = arow[tr * 4 + i];
    #pragma unroll
    for (int i = 0; i < 4; ++i)
      #pragma unroll
      for (int j = 0; j < 4; ++j)
        o[i][j] *= al[i];
    #pragma unroll 16
    for (int s = 0; s < 64; ++s) {
      float4 vv = *reinterpret_cast<const float4*>(&sV[s][tc * 4]);
      float vb[4] = {vv.x, vv.y, vv.z, vv.w};
      #pragma unroll
      for (int i = 0; i < 4; ++i) {
        float p = sP[tr * 4 + i][s];
        #pragma unroll
        for (int j = 0; j < 4; ++j)
          o[i][j] = fmaf(p, vb[j], o[i][j]);
      }
    }
  }

  // Finalize: divide by l, write out[b, t, h*HS + d]
  #pragma unroll
  for (int i = 0; i < 4; ++i) {
    const float il = 1.0f / lrow[tr * 4 + i];
    float4 ov = make_float4(o[i][0] * il, o[i][1] * il, o[i][2] * il, o[i][3] * il);
    *reinterpret_cast<float4*>(
        out + ((size_t)(b * T_ + t0 + tr * 4 + i) * C_) + h * HS_ + tc * 4) = ov;
  }
}

extern "C" void kernel_launch(void* const* d_in, const int* in_sizes, int n_in,
                              void* d_out, int out_size, void* d_ws, size_t ws_size,
                              hipStream_t stream)
{
  const float* x   = (const float*)d_in[0];
  const float* Wq  = (const float*)d_in[1];
  const float* Wk  = (const float*)d_in[2];
  const float* Wv  = (const float*)d_in[3];
  const float* Wo  = (const float*)d_in[4];
  const float* bo  = (const float*)d_in[5];
  const float* W1  = (const float*)d_in[6];
  const float* b1  = (const float*)d_in[7];
  const float* W2  = (const float*)d_in[8];
  const float* b2  = (const float*)d_in[9];
  const float* g1  = (const float*)d_in[10];
  const float* be1 = (const float*)d_in[11];
  const float* g2  = (const float*)d_in[12];
  const float* be2 = (const float*)d_in[13];
  float* out = (float*)d_out;

  float* ws = (float*)d_ws;
  const size_t S1 = (size_t)N_ROWS * C_;   // 4M floats
  float* ln1  = ws;
  float* qb   = ws + S1;
  float* kb   = ws + 2 * S1;
  float* vb   = ws + 3 * S1;
  float* attn = ws + 4 * S1;
  float* x2   = ws + 5 * S1;
  float* ln2  = ws;          // reuse ln1 (dead after Wo gemm)
  float* hb   = ws + S1;     // reuse q/k/v/attn (dead after attention+Wo)
  // total: 6*S1 floats = 96 MB

  dim3 blk(256);
  ln_kernel<<<dim3(N_ROWS), blk, 0, stream>>>(x, g1, be1, ln1);

  dim3 gq(N_ROWS / 64, C_ / 64);
  gemm_kernel<1, false, false, false><<<gq, blk, 0, stream>>>(ln1, Wq, nullptr, nullptr, qb, N_ROWS, C_, C_);
  gemm_kernel<1, false, false, false><<<gq, blk, 0, stream>>>(ln1, Wk, nullptr, nullptr, kb, N_ROWS, C_, C_);
  gemm_kernel<1, false, false, false><<<gq, blk, 0, stream>>>(ln1, Wv, nullptr, nullptr, vb, N_ROWS, C_, C_);

  dim3 ga(T_ / 64, B_ * H_);
  attn_kernel<<<ga, blk, 0, stream>>>(qb, kb, vb, attn);

  gemm_kernel<0, false, true, true><<<gq, blk, 0, stream>>>(attn, Wo, bo, ln1, x2, N_ROWS, C_, C_);

  ln_kernel<<<dim3(N_ROWS), blk, 0, stream>>>(x2, g2, be2, ln2);

  dim3 gmlp1(N_ROWS / 64, (4 * C_) / 64);
  gemm_kernel<0, true, true, false><<<gmlp1, blk, 0, stream>>>(ln2, W1, b1, nullptr, hb, N_ROWS, 4 * C_, C_);

  // NOTE: reference rebinds x to layernorm output before the MLP, so the
  // final residual is ln2 (NOT the pre-LN x2).
  gemm_kernel<0, false, true, true><<<gq, blk, 0, stream>>>(hb, W2, b2, ln2, out, N_ROWS, C_, 4 * C_);
}

// Round 3
// 1010.574 us; speedup vs baseline: 2.1781x; 2.1781x over previous
//
#include <hip/hip_runtime.h>
#include <hip/hip_bf16.h>
#include <math.h>

#define B_ 2
#define T_ 2048
#define C_ 1024
#define H_ 16
#define HS_ 64
#define N_ROWS (B_*T_)   // 4096
#define MB (1024*1024)

typedef __attribute__((ext_vector_type(8))) short bf16x8;
typedef __attribute__((ext_vector_type(4))) float floatx4;

static __device__ __forceinline__ unsigned short f2bf(float f) {
  union { float f; unsigned u; } v; v.f = f;
  unsigned r = v.u + 0x7fff + ((v.u >> 16) & 1);   // round-to-nearest-even
  return (unsigned short)(r >> 16);
}
static __device__ __forceinline__ float bf2f(unsigned short s) {
  union { unsigned u; float f; } v; v.u = ((unsigned)s) << 16;
  return v.f;
}

// ---------------- LayerNorm: one block per row, bf16 output ----------------
__global__ __launch_bounds__(256) void ln_kernel(
    const float* __restrict__ x, const float* __restrict__ g,
    const float* __restrict__ b, unsigned short* __restrict__ outb)
{
  const int row = blockIdx.x;
  const int tid = threadIdx.x;
  const float* xr = x + (size_t)row * C_;
  float4 xv = *reinterpret_cast<const float4*>(xr + tid * 4);
  float s  = xv.x + xv.y + xv.z + xv.w;
  float ss = xv.x*xv.x + xv.y*xv.y + xv.z*xv.z + xv.w*xv.w;
  #pragma unroll
  for (int off = 32; off > 0; off >>= 1) {
    s  += __shfl_down(s, off, 64);
    ss += __shfl_down(ss, off, 64);
  }
  __shared__ float rs[4], rss[4];
  __shared__ float smu, srstd;
  if ((tid & 63) == 0) { rs[tid >> 6] = s; rss[tid >> 6] = ss; }
  __syncthreads();
  if (tid == 0) {
    float S  = rs[0] + rs[1] + rs[2] + rs[3];
    float SS = rss[0] + rss[1] + rss[2] + rss[3];
    float mu  = S * (1.0f / C_);
    float var = SS * (1.0f / C_) - mu * mu;
    smu = mu; srstd = rsqrtf(var + 1e-5f);
  }
  __syncthreads();
  const float mu = smu, rstd = srstd;
  float4 gv = *reinterpret_cast<const float4*>(g + tid * 4);
  float4 bv = *reinterpret_cast<const float4*>(b + tid * 4);
  union { unsigned long long ll; unsigned short s[4]; } o;
  o.s[0] = f2bf((xv.x - mu) * rstd * gv.x + bv.x);
  o.s[1] = f2bf((xv.y - mu) * rstd * gv.y + bv.y);
  o.s[2] = f2bf((xv.z - mu) * rstd * gv.z + bv.z);
  o.s[3] = f2bf((xv.w - mu) * rstd * gv.w + bv.w);
  *reinterpret_cast<unsigned long long*>(outb + (size_t)row * C_ + tid * 4) = o.ll;
}

// ---------------- Transpose + cast: fp32 [R][Cc] -> bf16 [Cc][R], batched ---
__global__ __launch_bounds__(256) void transpose_cast(
    const float* __restrict__ in, unsigned short* __restrict__ out, int R, int Cc)
{
  __shared__ float tile[32][33];
  const int bz = blockIdx.z;
  in  += (size_t)bz * R * Cc;
  out += (size_t)bz * R * Cc;
  const int tx = threadIdx.x & 31;
  const int ty = threadIdx.x >> 5;    // 0..7
  const int c0 = blockIdx.x * 32, r0 = blockIdx.y * 32;
  #pragma unroll
  for (int j = 0; j < 4; ++j)
    tile[ty + j*8][tx] = in[(size_t)(r0 + ty + j*8) * Cc + c0 + tx];
  __syncthreads();
  #pragma unroll
  for (int j = 0; j < 4; ++j)
    out[(size_t)(c0 + ty + j*8) * R + r0 + tx] = f2bf(tile[tx][ty + j*8]);
}

// ---------------- bf16 MFMA GEMM (m97 structure) ----------------
// C[M,N] = A[M,K] @ Bt[N,K]^T (+bias) (+relu) (+bf16 res).
// 128x128 tile, 256 thr = 4 waves (2x2 of 64x64), BK=32, 16x16x32 MFMA.
template<bool OUTBF16, bool RELU, bool HASB, bool HASRES>
__global__ __launch_bounds__(256) void gemm_bf16(
    const unsigned short* __restrict__ A,   // [M][K] bf16
    const unsigned short* __restrict__ Bt,  // [N][K] bf16
    const float* __restrict__ bias,         // [N] fp32
    const unsigned short* __restrict__ res, // [M][N] bf16
    void* __restrict__ Cout,                // [M][N] fp32 or bf16
    int M, int N, int K)
{
  __shared__ unsigned short As[128 * 32];   // [m][k] row-major, 64B rows
  __shared__ unsigned short Bs[128 * 32];   // [n][k]
  const int tid  = threadIdx.x;
  const int lane = tid & 63;
  const int wave = tid >> 6;
  const int wm = wave & 1, wn = wave >> 1;
  const int m0 = blockIdx.x * 128, n0 = blockIdx.y * 128;

  const int lrow = lane >> 2;          // 0..15 (16 rows per issue per wave)
  const int lcol = (lane & 3) * 8;     // k-element offset (8 bf16 = 16B)
  const int fr = lane & 15;            // MFMA fragment row/col
  const int fq = lane >> 4;            // quad

  floatx4 acc[4][4] = {};

  const unsigned short* Aw = A  + (size_t)m0 * K;
  const unsigned short* Bw = Bt + (size_t)n0 * K;

  for (int k0 = 0; k0 < K; k0 += 32) {
    __syncthreads();   // previous compute done before overwriting LDS
    #pragma unroll
    for (int i = 0; i < 2; ++i) {
      const int rbase = i * 64 + wave * 16;                 // wave-uniform
      const unsigned short* gp = Aw + (size_t)(rbase + lrow) * K + k0 + lcol;
      __builtin_amdgcn_global_load_lds(
          (const __attribute__((address_space(1))) void*)gp,
          (__attribute__((address_space(3))) void*)(As + rbase * 32),
          16, 0, 0);
    }
    #pragma unroll
    for (int i = 0; i < 2; ++i) {
      const int rbase = i * 64 + wave * 16;
      const unsigned short* gp = Bw + (size_t)(rbase + lrow) * K + k0 + lcol;
      __builtin_amdgcn_global_load_lds(
          (const __attribute__((address_space(1))) void*)gp,
          (__attribute__((address_space(3))) void*)(Bs + rbase * 32),
          16, 0, 0);
    }
    __syncthreads();   // compiler drains vmcnt before barrier -> loads visible

    bf16x8 af[4], bfr[4];
    #pragma unroll
    for (int t = 0; t < 4; ++t) {
      af[t]  = *reinterpret_cast<const bf16x8*>(As + (wm*64 + t*16 + fr)*32 + fq*8);
      bfr[t] = *reinterpret_cast<const bf16x8*>(Bs + (wn*64 + t*16 + fr)*32 + fq*8);
    }
    #pragma unroll
    for (int mt = 0; mt < 4; ++mt)
      #pragma unroll
      for (int nt = 0; nt < 4; ++nt)
        acc[mt][nt] = __builtin_amdgcn_mfma_f32_16x16x32_bf16(
            af[mt], bfr[nt], acc[mt][nt], 0, 0, 0);
  }

  // Epilogue. C/D layout (m89): col = lane&15, row = (lane>>4)*4 + r.
  #pragma unroll
  for (int nt = 0; nt < 4; ++nt) {
    const int col = n0 + wn*64 + nt*16 + fr;
    const float bv = HASB ? bias[col] : 0.0f;
    #pragma unroll
    for (int mt = 0; mt < 4; ++mt) {
      #pragma unroll
      for (int r = 0; r < 4; ++r) {
        const int row = m0 + wm*64 + mt*16 + fq*4 + r;
        float v = acc[mt][nt][r] + bv;
        if (RELU) v = v > 0.0f ? v : 0.0f;
        if (HASRES) v += bf2f(res[(size_t)row * N + col]);
        if (OUTBF16) ((unsigned short*)Cout)[(size_t)row * N + col] = f2bf(v);
        else         ((float*)Cout)[(size_t)row * N + col] = v;
      }
    }
  }
}

// ---------------- Flash-style causal attention (fp32, fused-QKV input) -----
// qkv: [B*T][3072] rows = [q(1024) | k(1024) | v(1024)], head h at h*64.
// out: bf16 [B*T][1024]. One block per (q-tile of 64, b*H+h).
__global__ __launch_bounds__(256) void attn_kernel(
    const float* __restrict__ qkv, unsigned short* __restrict__ out)
{
  const int qt = (gridDim.x - 1) - blockIdx.x;   // longest blocks first
  const int bh = blockIdx.y;
  const int b  = bh >> 4;
  const int h  = bh & 15;
  const int tid = threadIdx.x;
  const int tr = tid >> 4, tc = tid & 15;
  const int t0 = qt * 64;
  const int QS = 3 * C_;   // 3072 row stride

  __shared__ __align__(16) float sQt[64][68];
  __shared__ __align__(16) float sKt[64][68];
  __shared__ __align__(16) float sV [64][68];
  __shared__ __align__(16) float sP [64][68];
  __shared__ float mrow[64], lrow[64], arow[64];

  {
    const int r  = tid >> 2;
    const int c0 = (tid & 3) * 16;
    const float* src = qkv + (size_t)(b * T_ + t0 + r) * QS + h * HS_ + c0;
    #pragma unroll
    for (int u = 0; u < 4; ++u) {
      float4 t = *reinterpret_cast<const float4*>(src + u * 4);
      sQt[c0 + u*4 + 0][r] = t.x;
      sQt[c0 + u*4 + 1][r] = t.y;
      sQt[c0 + u*4 + 2][r] = t.z;
      sQt[c0 + u*4 + 3][r] = t.w;
    }
  }
  if (tid < 64) { mrow[tid] = -3.0e38f; lrow[tid] = 0.0f; }

  float o[4][4] = {};

  for (int ks = 0; ks <= qt; ++ks) {
    __syncthreads();
    {
      const int r  = tid >> 2;
      const int c0 = (tid & 3) * 16;
      const float* ksrc = qkv + (size_t)(b * T_ + ks * 64 + r) * QS + C_   + h * HS_ + c0;
      const float* vsrc = qkv + (size_t)(b * T_ + ks * 64 + r) * QS + 2*C_ + h * HS_ + c0;
      #pragma unroll
      for (int u = 0; u < 4; ++u) {
        float4 t = *reinterpret_cast<const float4*>(ksrc + u * 4);
        sKt[c0 + u*4 + 0][r] = t.x;
        sKt[c0 + u*4 + 1][r] = t.y;
        sKt[c0 + u*4 + 2][r] = t.z;
        sKt[c0 + u*4 + 3][r] = t.w;
        *reinterpret_cast<float4*>(&sV[r][c0 + u*4]) =
            *reinterpret_cast<const float4*>(vsrc + u * 4);
      }
    }
    __syncthreads();

    float sacc[4][4] = {};
    #pragma unroll 16
    for (int d = 0; d < 64; ++d) {
      float4 a  = *reinterpret_cast<const float4*>(&sQt[d][tr * 4]);
      float4 bb = *reinterpret_cast<const float4*>(&sKt[d][tc * 4]);
      float aa[4] = {a.x, a.y, a.z, a.w};
      float bv[4] = {bb.x, bb.y, bb.z, bb.w};
      #pragma unroll
      for (int i = 0; i < 4; ++i)
        #pragma unroll
        for (int j = 0; j < 4; ++j)
          sacc[i][j] = fmaf(aa[i], bv[j], sacc[i][j]);
    }
    const float scale = 0.03125f;  // C^-0.5
    #pragma unroll
    for (int i = 0; i < 4; ++i) {
      #pragma unroll
      for (int j = 0; j < 4; ++j) {
        if (ks == qt) {
          const int rg = t0 + tr * 4 + i;
          const int cg = ks * 64 + tc * 4 + j;
          sacc[i][j] = (cg <= rg) ? sacc[i][j] * scale : -3.0e38f;
        } else {
          sacc[i][j] *= scale;
        }
      }
      float4 w = make_float4(sacc[i][0], sacc[i][1], sacc[i][2], sacc[i][3]);
      *reinterpret_cast<float4*>(&sP[tr * 4 + i][tc * 4]) = w;
    }
    __syncthreads();

    if (tid < 64) {
      float m_old = mrow[tid];
      float m = m_old;
      float* pr = sP[tid];
      for (int j = 0; j < 64; ++j) m = fmaxf(m, pr[j]);
      float sum = 0.0f;
      for (int j = 0; j < 64; ++j) {
        float e = __expf(pr[j] - m);
        pr[j] = e;
        sum += e;
      }
      float alpha = __expf(m_old - m);
      lrow[tid] = lrow[tid] * alpha + sum;
      mrow[tid] = m;
      arow[tid] = alpha;
    }
    __syncthreads();

    float al[4];
    #pragma unroll
    for (int i = 0; i < 4; ++i) al[i] = arow[tr * 4 + i];
    #pragma unroll
    for (int i = 0; i < 4; ++i)
      #pragma unroll
      for (int j = 0; j < 4; ++j)
        o[i][j] *= al[i];
    #pragma unroll 16
    for (int s = 0; s < 64; ++s) {
      float4 vv = *reinterpret_cast<const float4*>(&sV[s][tc * 4]);
      float vb[4] = {vv.x, vv.y, vv.z, vv.w};
      #pragma unroll
      for (int i = 0; i < 4; ++i) {
        float p = sP[tr * 4 + i][s];
        #pragma unroll
        for (int j = 0; j < 4; ++j)
          o[i][j] = fmaf(p, vb[j], o[i][j]);
      }
    }
  }

  #pragma unroll
  for (int i = 0; i < 4; ++i) {
    const float il = 1.0f / lrow[tr * 4 + i];
    union { unsigned long long ll; unsigned short s[4]; } u;
    u.s[0] = f2bf(o[i][0] * il); u.s[1] = f2bf(o[i][1] * il);
    u.s[2] = f2bf(o[i][2] * il); u.s[3] = f2bf(o[i][3] * il);
    *reinterpret_cast<unsigned long long*>(
        out + (size_t)(b * T_ + t0 + tr * 4 + i) * C_ + h * HS_ + tc * 4) = u.ll;
  }
}

extern "C" void kernel_launch(void* const* d_in, const int* in_sizes, int n_in,
                              void* d_out, int out_size, void* d_ws, size_t ws_size,
                              hipStream_t stream)
{
  const float* x   = (const float*)d_in[0];
  const float* Wq  = (const float*)d_in[1];
  const float* Wk  = (const float*)d_in[2];
  const float* Wv  = (const float*)d_in[3];
  const float* Wo  = (const float*)d_in[4];
  const float* bo  = (const float*)d_in[5];
  const float* W1  = (const float*)d_in[6];
  const float* b1  = (const float*)d_in[7];
  const float* W2  = (const float*)d_in[8];
  const float* b2  = (const float*)d_in[9];
  const float* g1  = (const float*)d_in[10];
  const float* be1 = (const float*)d_in[11];
  const float* g2  = (const float*)d_in[12];
  const float* be2 = (const float*)d_in[13];
  float* out = (float*)d_out;

  // Workspace layout (88 MB, liveness-based reuse):
  char* ws = (char*)d_ws;
  unsigned short* BtQKV = (unsigned short*)(ws + (size_t) 0*MB);  // [3072][1024] 6MB
  unsigned short* BtWo  = (unsigned short*)(ws + (size_t) 6*MB);  // [1024][1024] 2MB
  unsigned short* BtW1  = (unsigned short*)(ws + (size_t) 8*MB);  // [4096][1024] 8MB
  unsigned short* BtW2  = (unsigned short*)(ws + (size_t)16*MB);  // [1024][4096] 8MB
  unsigned short* lnb   = (unsigned short*)(ws + (size_t)24*MB);  // ln1/ln2 bf16 8MB
  float*          qkv   = (float*)         (ws + (size_t)32*MB);  // [4096][3072] 48MB
  float*          x2    = (float*)         (ws + (size_t)32*MB);  // 16MB (qkv dead)
  unsigned short* hb    = (unsigned short*)(ws + (size_t)48*MB);  // [4096][4096] 32MB
  unsigned short* attnb = (unsigned short*)(ws + (size_t)80*MB);  // [4096][1024] 8MB

  dim3 blk(256);

  // Weight transposes fp32->bf16 [N][K]
  transpose_cast<<<dim3(HS_/32, C_/32, H_), blk, 0, stream>>>(Wq, BtQKV,              C_, HS_);
  transpose_cast<<<dim3(HS_/32, C_/32, H_), blk, 0, stream>>>(Wk, BtQKV + 1024*1024,  C_, HS_);
  transpose_cast<<<dim3(HS_/32, C_/32, H_), blk, 0, stream>>>(Wv, BtQKV + 2*1024*1024,C_, HS_);
  transpose_cast<<<dim3(C_/32,  C_/32, 1),  blk, 0, stream>>>(Wo, BtWo, C_, C_);
  transpose_cast<<<dim3(4*C_/32,C_/32, 1),  blk, 0, stream>>>(W1, BtW1, C_, 4*C_);
  transpose_cast<<<dim3(C_/32,4*C_/32, 1),  blk, 0, stream>>>(W2, BtW2, 4*C_, C_);

  // LN1
  ln_kernel<<<dim3(N_ROWS), blk, 0, stream>>>(x, g1, be1, lnb);

  // Fused QKV GEMM: [4096][1024] @ [3072][1024]^T -> fp32 [4096][3072]
  gemm_bf16<false,false,false,false><<<dim3(N_ROWS/128, 3072/128), blk, 0, stream>>>(
      lnb, BtQKV, nullptr, nullptr, qkv, N_ROWS, 3072, C_);

  // Flash attention -> bf16 attnb
  attn_kernel<<<dim3(T_/64, B_*H_), blk, 0, stream>>>(qkv, attnb);

  // Wo GEMM + bias + residual(ln1) -> fp32 x2
  gemm_bf16<false,false,true,true><<<dim3(N_ROWS/128, C_/128), blk, 0, stream>>>(
      attnb, BtWo, bo, lnb, x2, N_ROWS, C_, C_);

  // LN2 (overwrites lnb; Wo GEMM already consumed ln1)
  ln_kernel<<<dim3(N_ROWS), blk, 0, stream>>>(x2, g2, be2, lnb);

  // W1 GEMM + bias + ReLU -> bf16 hb
  gemm_bf16<true,true,true,false><<<dim3(N_ROWS/128, 4*C_/128), blk, 0, stream>>>(
      lnb, BtW1, b1, nullptr, hb, N_ROWS, 4*C_, C_);

  // W2 GEMM + bias + residual(ln2!) -> fp32 out
  // (reference rebinds x to LN2 output before the MLP)
  gemm_bf16<false,false,true,true><<<dim3(N_ROWS/128, C_/128), blk, 0, stream>>>(
      hb, BtW2, b2, lnb, out, N_ROWS, C_, 4*C_);
}

// Round 4
// 480.733 us; speedup vs baseline: 4.5787x; 2.1022x over previous
//
#include <hip/hip_runtime.h>
#include <hip/hip_bf16.h>
#include <math.h>

#define B_ 2
#define T_ 2048
#define C_ 1024
#define H_ 16
#define HS_ 64
#define N_ROWS (B_*T_)   // 4096
#define MB (1024*1024)

typedef __attribute__((ext_vector_type(8))) short bf16x8;
typedef __attribute__((ext_vector_type(8))) unsigned short u16x8;
typedef __attribute__((ext_vector_type(4))) float floatx4;

static __device__ __forceinline__ unsigned short f2bf(float f) {
  union { float f; unsigned u; } v; v.f = f;
  unsigned r = v.u + 0x7fff + ((v.u >> 16) & 1);   // round-to-nearest-even
  return (unsigned short)(r >> 16);
}
static __device__ __forceinline__ float bf2f(unsigned short s) {
  union { unsigned u; float f; } v; v.u = ((unsigned)s) << 16;
  return v.f;
}

// ---------------- LayerNorm: one block per row, bf16 output ----------------
__global__ __launch_bounds__(256) void ln_kernel(
    const float* __restrict__ x, const float* __restrict__ g,
    const float* __restrict__ b, unsigned short* __restrict__ outb)
{
  const int row = blockIdx.x;
  const int tid = threadIdx.x;
  const float* xr = x + (size_t)row * C_;
  float4 xv = *reinterpret_cast<const float4*>(xr + tid * 4);
  float s  = xv.x + xv.y + xv.z + xv.w;
  float ss = xv.x*xv.x + xv.y*xv.y + xv.z*xv.z + xv.w*xv.w;
  #pragma unroll
  for (int off = 32; off > 0; off >>= 1) {
    s  += __shfl_down(s, off, 64);
    ss += __shfl_down(ss, off, 64);
  }
  __shared__ float rs[4], rss[4];
  __shared__ float smu, srstd;
  if ((tid & 63) == 0) { rs[tid >> 6] = s; rss[tid >> 6] = ss; }
  __syncthreads();
  if (tid == 0) {
    float S  = rs[0] + rs[1] + rs[2] + rs[3];
    float SS = rss[0] + rss[1] + rss[2] + rss[3];
    float mu  = S * (1.0f / C_);
    float var = SS * (1.0f / C_) - mu * mu;
    smu = mu; srstd = rsqrtf(var + 1e-5f);
  }
  __syncthreads();
  const float mu = smu, rstd = srstd;
  float4 gv = *reinterpret_cast<const float4*>(g + tid * 4);
  float4 bv = *reinterpret_cast<const float4*>(b + tid * 4);
  union { unsigned long long ll; unsigned short s[4]; } o;
  o.s[0] = f2bf((xv.x - mu) * rstd * gv.x + bv.x);
  o.s[1] = f2bf((xv.y - mu) * rstd * gv.y + bv.y);
  o.s[2] = f2bf((xv.z - mu) * rstd * gv.z + bv.z);
  o.s[3] = f2bf((xv.w - mu) * rstd * gv.w + bv.w);
  *reinterpret_cast<unsigned long long*>(outb + (size_t)row * C_ + tid * 4) = o.ll;
}

// ---------------- Transpose + cast: fp32 [R][Cc] -> bf16 [Cc][R], batched ---
__global__ __launch_bounds__(256) void transpose_cast(
    const float* __restrict__ in, unsigned short* __restrict__ out, int R, int Cc)
{
  __shared__ float tile[32][33];
  const int bz = blockIdx.z;
  in  += (size_t)bz * R * Cc;
  out += (size_t)bz * R * Cc;
  const int tx = threadIdx.x & 31;
  const int ty = threadIdx.x >> 5;    // 0..7
  const int c0 = blockIdx.x * 32, r0 = blockIdx.y * 32;
  #pragma unroll
  for (int j = 0; j < 4; ++j)
    tile[ty + j*8][tx] = in[(size_t)(r0 + ty + j*8) * Cc + c0 + tx];
  __syncthreads();
  #pragma unroll
  for (int j = 0; j < 4; ++j)
    out[(size_t)(c0 + ty + j*8) * R + r0 + tx] = f2bf(tile[tx][ty + j*8]);
}

// ---------------- bf16 MFMA GEMM (m97 structure) ----------------
template<bool OUTBF16, bool RELU, bool HASB, bool HASRES>
__global__ __launch_bounds__(256) void gemm_bf16(
    const unsigned short* __restrict__ A,   // [M][K] bf16
    const unsigned short* __restrict__ Bt,  // [N][K] bf16
    const float* __restrict__ bias,         // [N] fp32
    const unsigned short* __restrict__ res, // [M][N] bf16
    void* __restrict__ Cout,                // [M][N] fp32 or bf16
    int M, int N, int K)
{
  __shared__ unsigned short As[128 * 32];
  __shared__ unsigned short Bs[128 * 32];
  const int tid  = threadIdx.x;
  const int lane = tid & 63;
  const int wave = tid >> 6;
  const int wm = wave & 1, wn = wave >> 1;
  const int m0 = blockIdx.x * 128, n0 = blockIdx.y * 128;

  const int lrow = lane >> 2;
  const int lcol = (lane & 3) * 8;
  const int fr = lane & 15;
  const int fq = lane >> 4;

  floatx4 acc[4][4] = {};

  const unsigned short* Aw = A  + (size_t)m0 * K;
  const unsigned short* Bw = Bt + (size_t)n0 * K;

  for (int k0 = 0; k0 < K; k0 += 32) {
    __syncthreads();
    #pragma unroll
    for (int i = 0; i < 2; ++i) {
      const int rbase = i * 64 + wave * 16;
      const unsigned short* gp = Aw + (size_t)(rbase + lrow) * K + k0 + lcol;
      __builtin_amdgcn_global_load_lds(
          (const __attribute__((address_space(1))) void*)gp,
          (__attribute__((address_space(3))) void*)(As + rbase * 32),
          16, 0, 0);
    }
    #pragma unroll
    for (int i = 0; i < 2; ++i) {
      const int rbase = i * 64 + wave * 16;
      const unsigned short* gp = Bw + (size_t)(rbase + lrow) * K + k0 + lcol;
      __builtin_amdgcn_global_load_lds(
          (const __attribute__((address_space(1))) void*)gp,
          (__attribute__((address_space(3))) void*)(Bs + rbase * 32),
          16, 0, 0);
    }
    __syncthreads();

    bf16x8 af[4], bfr[4];
    #pragma unroll
    for (int t = 0; t < 4; ++t) {
      af[t]  = *reinterpret_cast<const bf16x8*>(As + (wm*64 + t*16 + fr)*32 + fq*8);
      bfr[t] = *reinterpret_cast<const bf16x8*>(Bs + (wn*64 + t*16 + fr)*32 + fq*8);
    }
    #pragma unroll
    for (int mt = 0; mt < 4; ++mt)
      #pragma unroll
      for (int nt = 0; nt < 4; ++nt)
        acc[mt][nt] = __builtin_amdgcn_mfma_f32_16x16x32_bf16(
            af[mt], bfr[nt], acc[mt][nt], 0, 0, 0);
  }

  #pragma unroll
  for (int nt = 0; nt < 4; ++nt) {
    const int col = n0 + wn*64 + nt*16 + fr;
    const float bv = HASB ? bias[col] : 0.0f;
    #pragma unroll
    for (int mt = 0; mt < 4; ++mt) {
      #pragma unroll
      for (int r = 0; r < 4; ++r) {
        const int row = m0 + wm*64 + mt*16 + fq*4 + r;
        float v = acc[mt][nt][r] + bv;
        if (RELU) v = v > 0.0f ? v : 0.0f;
        if (HASRES) v += bf2f(res[(size_t)row * N + col]);
        if (OUTBF16) ((unsigned short*)Cout)[(size_t)row * N + col] = f2bf(v);
        else         ((float*)Cout)[(size_t)row * N + col] = v;
      }
    }
  }
}

// ---------------- V transpose: qkv V-part -> vt[bh][64 d][2048 t] bf16 -----
__global__ __launch_bounds__(256) void v_transpose(
    const unsigned short* __restrict__ qkv, unsigned short* __restrict__ vt)
{
  __shared__ __align__(16) unsigned short sT[64][72];
  const int st = blockIdx.x;        // s-tile of 64
  const int bh = blockIdx.y;
  const int b = bh >> 4, h = bh & 15;
  const int t = threadIdx.x;
  const int r = t >> 2, c0 = (t & 3) * 16;
  const unsigned short* src =
      qkv + (size_t)(b * T_ + st * 64 + r) * 3072 + 2048 + h * 64 + c0;
  *(u16x8*)&sT[r][c0]     = *(const u16x8*)src;
  *(u16x8*)&sT[r][c0 + 8] = *(const u16x8*)(src + 8);
  __syncthreads();
  const int d = t >> 2, sc = (t & 3) * 16;
  unsigned short v[16];
  #pragma unroll
  for (int j = 0; j < 16; ++j) v[j] = sT[sc + j][d];
  unsigned short* dst = vt + ((size_t)bh * 64 + d) * (size_t)T_ + st * 64 + sc;
  *(uint4*)dst       = *(uint4*)&v[0];
  *(uint4*)(dst + 8) = *(uint4*)&v[8];
}

// ---------------- MFMA flash attention ----------------
// qkv bf16 [B*T][3072] (q|k|v), vt bf16 [32 bh][64 d][2048 t].
// Block: 256 thr = 4 waves; Q-tile 128 (32 rows/wave); K-tile 64.
__global__ __launch_bounds__(256) void attn_mfma(
    const unsigned short* __restrict__ qkv,
    const unsigned short* __restrict__ vt,
    unsigned short* __restrict__ out)
{
  const int bh = blockIdx.x;
  const int qt = (int)(gridDim.y - 1) - (int)blockIdx.y;  // long blocks first
  const int b = bh >> 4, h = bh & 15;
  const int tid = threadIdx.x;
  const int w = tid >> 6;
  const int lane = tid & 63;
  const int l15 = lane & 15, fq = lane >> 4;
  const int t0 = qt * 128;

  __shared__ __align__(16) unsigned short sK [64][72];
  __shared__ __align__(16) unsigned short sVt[64][72];
  __shared__ __align__(16) unsigned short sP [128][72];

  // Q fragments in registers: rows t0 + w*32 + mt*16 + l15, d chunks c*32
  bf16x8 aq[2][2];
  #pragma unroll
  for (int mt = 0; mt < 2; ++mt) {
    const int qr = t0 + w*32 + mt*16 + l15;
    const unsigned short* qp = qkv + (size_t)(b*T_ + qr)*3072 + h*HS_ + fq*8;
    aq[mt][0] = *(const bf16x8*)qp;
    aq[mt][1] = *(const bf16x8*)(qp + 32);
  }

  floatx4 oacc[2][4] = {};
  float m_s[2][4], l_s[2][4];
  #pragma unroll
  for (int mt = 0; mt < 2; ++mt)
    #pragma unroll
    for (int r = 0; r < 4; ++r) { m_s[mt][r] = -3.0e38f; l_s[mt][r] = 0.0f; }

  const int kdiag = t0 >> 6;
  const int nks = kdiag + 2;                      // key tiles 0 .. kdiag+1
  const float c1 = 1.4426950408889634f / 32.0f;   // log2(e) * C^-0.5

  for (int ks = 0; ks < nks; ++ks) {
    __syncthreads();
    {   // stage K tile and Vt tile
      const int r = tid >> 2, c0 = (tid & 3) * 16;
      const unsigned short* kp =
          qkv + (size_t)(b*T_ + ks*64 + r)*3072 + C_ + h*HS_ + c0;
      u16x8 k0 = *(const u16x8*)kp, k1 = *(const u16x8*)(kp + 8);
      const unsigned short* vp =
          vt + ((size_t)bh*64 + r)*(size_t)T_ + ks*64 + c0;
      u16x8 v0 = *(const u16x8*)vp, v1 = *(const u16x8*)(vp + 8);
      *(u16x8*)&sK[r][c0]      = k0; *(u16x8*)&sK[r][c0 + 8]  = k1;
      *(u16x8*)&sVt[r][c0]     = v0; *(u16x8*)&sVt[r][c0 + 8] = v1;
    }
    __syncthreads();

    // S = Q K^T   (rows: mt*16 + fq*4 + r, cols: nt*16 + l15)
    floatx4 sacc[2][4] = {};
    #pragma unroll
    for (int c = 0; c < 2; ++c) {
      #pragma unroll
      for (int nt = 0; nt < 4; ++nt) {
        bf16x8 bk = *(const bf16x8*)&sK[nt*16 + l15][c*32 + fq*8];
        #pragma unroll
        for (int mt = 0; mt < 2; ++mt)
          sacc[mt][nt] = __builtin_amdgcn_mfma_f32_16x16x32_bf16(
              aq[mt][c], bk, sacc[mt][nt], 0, 0, 0);
      }
    }

    // causal mask (only the last two key tiles can touch the diagonal)
    if (ks >= kdiag) {
      #pragma unroll
      for (int mt = 0; mt < 2; ++mt)
        #pragma unroll
        for (int nt = 0; nt < 4; ++nt) {
          const int key = ks*64 + nt*16 + l15;
          #pragma unroll
          for (int r = 0; r < 4; ++r) {
            const int qrow = t0 + w*32 + mt*16 + fq*4 + r;
            if (key > qrow) sacc[mt][nt][r] = -3.0e38f;
          }
        }
    }

    // online softmax (per row; rows replicated across the 16 lanes of a quad)
    float alpha_[2][4];
    #pragma unroll
    for (int mt = 0; mt < 2; ++mt) {
      #pragma unroll
      for (int r = 0; r < 4; ++r) {
        float mx = fmaxf(fmaxf(sacc[mt][0][r], sacc[mt][1][r]),
                         fmaxf(sacc[mt][2][r], sacc[mt][3][r]));
        mx = fmaxf(mx, __shfl_xor(mx, 1, 64));
        mx = fmaxf(mx, __shfl_xor(mx, 2, 64));
        mx = fmaxf(mx, __shfl_xor(mx, 4, 64));
        mx = fmaxf(mx, __shfl_xor(mx, 8, 64));
        const float mnew = fmaxf(m_s[mt][r], mx);
        const float alpha = exp2f((m_s[mt][r] - mnew) * c1);
        float sum = 0.0f;
        const int prow = w*32 + mt*16 + fq*4 + r;
        #pragma unroll
        for (int nt = 0; nt < 4; ++nt) {
          const float p = exp2f((sacc[mt][nt][r] - mnew) * c1);
          sP[prow][nt*16 + l15] = f2bf(p);
          sum += p;
        }
        sum += __shfl_xor(sum, 1, 64);
        sum += __shfl_xor(sum, 2, 64);
        sum += __shfl_xor(sum, 4, 64);
        sum += __shfl_xor(sum, 8, 64);
        l_s[mt][r] = l_s[mt][r] * alpha + sum;
        m_s[mt][r] = mnew;
        alpha_[mt][r] = alpha;
      }
    }

    // O *= alpha, then O += P @ V
    #pragma unroll
    for (int mt = 0; mt < 2; ++mt)
      #pragma unroll
      for (int dt = 0; dt < 4; ++dt)
        #pragma unroll
        for (int r = 0; r < 4; ++r)
          oacc[mt][dt][r] *= alpha_[mt][r];

    #pragma unroll
    for (int c = 0; c < 2; ++c) {
      bf16x8 ap0 = *(const bf16x8*)&sP[w*32 + l15][c*32 + fq*8];
      bf16x8 ap1 = *(const bf16x8*)&sP[w*32 + 16 + l15][c*32 + fq*8];
      #pragma unroll
      for (int dt = 0; dt < 4; ++dt) {
        bf16x8 bv = *(const bf16x8*)&sVt[dt*16 + l15][c*32 + fq*8];
        oacc[0][dt] = __builtin_amdgcn_mfma_f32_16x16x32_bf16(ap0, bv, oacc[0][dt], 0, 0, 0);
        oacc[1][dt] = __builtin_amdgcn_mfma_f32_16x16x32_bf16(ap1, bv, oacc[1][dt], 0, 0, 0);
      }
    }
  }

  // epilogue: O /= l, write bf16 [token][h*64 + d]
  #pragma unroll
  for (int mt = 0; mt < 2; ++mt) {
    float il[4];
    #pragma unroll
    for (int r = 0; r < 4; ++r) il[r] = 1.0f / l_s[mt][r];
    #pragma unroll
    for (int dt = 0; dt < 4; ++dt) {
      #pragma unroll
      for (int r = 0; r < 4; ++r) {
        const int qrow = t0 + w*32 + mt*16 + fq*4 + r;
        out[(size_t)(b*T_ + qrow)*C_ + h*HS_ + dt*16 + l15] =
            f2bf(oacc[mt][dt][r] * il[r]);
      }
    }
  }
}

extern "C" void kernel_launch(void* const* d_in, const int* in_sizes, int n_in,
                              void* d_out, int out_size, void* d_ws, size_t ws_size,
                              hipStream_t stream)
{
  const float* x   = (const float*)d_in[0];
  const float* Wq  = (const float*)d_in[1];
  const float* Wk  = (const float*)d_in[2];
  const float* Wv  = (const float*)d_in[3];
  const float* Wo  = (const float*)d_in[4];
  const float* bo  = (const float*)d_in[5];
  const float* W1  = (const float*)d_in[6];
  const float* b1  = (const float*)d_in[7];
  const float* W2  = (const float*)d_in[8];
  const float* b2  = (const float*)d_in[9];
  const float* g1  = (const float*)d_in[10];
  const float* be1 = (const float*)d_in[11];
  const float* g2  = (const float*)d_in[12];
  const float* be2 = (const float*)d_in[13];
  float* out = (float*)d_out;

  // Workspace (72 MB peak, liveness-based reuse):
  char* ws = (char*)d_ws;
  unsigned short* BtQKV = (unsigned short*)(ws + (size_t) 0*MB);  // 6MB
  unsigned short* BtWo  = (unsigned short*)(ws + (size_t) 6*MB);  // 2MB
  unsigned short* BtW1  = (unsigned short*)(ws + (size_t) 8*MB);  // 8MB
  unsigned short* BtW2  = (unsigned short*)(ws + (size_t)16*MB);  // 8MB
  unsigned short* lnb   = (unsigned short*)(ws + (size_t)24*MB);  // 8MB
  unsigned short* qkvb  = (unsigned short*)(ws + (size_t)32*MB);  // [4096][3072] 24MB
  unsigned short* vtb   = (unsigned short*)(ws + (size_t)56*MB);  // [32][64][2048] 8MB
  unsigned short* attnb = (unsigned short*)(ws + (size_t)64*MB);  // 8MB
  float*          x2    = (float*)         (ws + (size_t)32*MB);  // 16MB (qkv dead)
  unsigned short* hb    = (unsigned short*)(ws + (size_t)32*MB);  // 32MB (x2,vt dead)

  dim3 blk(256);

  transpose_cast<<<dim3(HS_/32, C_/32, H_), blk, 0, stream>>>(Wq, BtQKV,               C_, HS_);
  transpose_cast<<<dim3(HS_/32, C_/32, H_), blk, 0, stream>>>(Wk, BtQKV + 1024*1024,   C_, HS_);
  transpose_cast<<<dim3(HS_/32, C_/32, H_), blk, 0, stream>>>(Wv, BtQKV + 2*1024*1024, C_, HS_);
  transpose_cast<<<dim3(C_/32,  C_/32, 1),  blk, 0, stream>>>(Wo, BtWo, C_, C_);
  transpose_cast<<<dim3(4*C_/32,C_/32, 1),  blk, 0, stream>>>(W1, BtW1, C_, 4*C_);
  transpose_cast<<<dim3(C_/32,4*C_/32, 1),  blk, 0, stream>>>(W2, BtW2, 4*C_, C_);

  ln_kernel<<<dim3(N_ROWS), blk, 0, stream>>>(x, g1, be1, lnb);

  // Fused QKV GEMM -> bf16 [4096][3072]
  gemm_bf16<true,false,false,false><<<dim3(N_ROWS/128, 3072/128), blk, 0, stream>>>(
      lnb, BtQKV, nullptr, nullptr, qkvb, N_ROWS, 3072, C_);

  // V transpose -> vt[bh][d][t]
  v_transpose<<<dim3(T_/64, B_*H_), blk, 0, stream>>>(qkvb, vtb);

  // MFMA flash attention -> bf16 attnb
  attn_mfma<<<dim3(B_*H_, T_/128), blk, 0, stream>>>(qkvb, vtb, attnb);

  // Wo GEMM + bias + residual(ln1) -> fp32 x2
  gemm_bf16<false,false,true,true><<<dim3(N_ROWS/128, C_/128), blk, 0, stream>>>(
      attnb, BtWo, bo, lnb, x2, N_ROWS, C_, C_);

  // LN2
  ln_kernel<<<dim3(N_ROWS), blk, 0, stream>>>(x2, g2, be2, lnb);

  // W1 GEMM + bias + ReLU -> bf16 hb
  gemm_bf16<true,true,true,false><<<dim3(N_ROWS/128, 4*C_/128), blk, 0, stream>>>(
      lnb, BtW1, b1, nullptr, hb, N_ROWS, 4*C_, C_);

  // W2 GEMM + bias + residual(ln2) -> fp32 out
  gemm_bf16<false,false,true,true><<<dim3(N_ROWS/128, C_/128), blk, 0, stream>>>(
      hb, BtW2, b2, lnb, out, N_ROWS, C_, 4*C_);
}

// Round 5
// 409.218 us; speedup vs baseline: 5.3789x; 1.1748x over previous
//
#include <hip/hip_runtime.h>
#include <hip/hip_bf16.h>
#include <math.h>

#define B_ 2
#define T_ 2048
#define C_ 1024
#define H_ 16
#define HS_ 64
#define N_ROWS (B_*T_)   // 4096
#define MB (1024*1024)

typedef __attribute__((ext_vector_type(8))) short bf16x8;
typedef __attribute__((ext_vector_type(8))) unsigned short u16x8;
typedef __attribute__((ext_vector_type(4))) float floatx4;

static __device__ __forceinline__ unsigned short f2bf(float f) {
  union { float f; unsigned u; } v; v.f = f;
  unsigned r = v.u + 0x7fff + ((v.u >> 16) & 1);   // round-to-nearest-even
  return (unsigned short)(r >> 16);
}
static __device__ __forceinline__ float bf2f(unsigned short s) {
  union { unsigned u; float f; } v; v.u = ((unsigned)s) << 16;
  return v.f;
}

// ---------------- LayerNorm: one block per row, bf16 output ----------------
__global__ __launch_bounds__(256) void ln_kernel(
    const float* __restrict__ x, const float* __restrict__ g,
    const float* __restrict__ b, unsigned short* __restrict__ outb)
{
  const int row = blockIdx.x;
  const int tid = threadIdx.x;
  const float* xr = x + (size_t)row * C_;
  float4 xv = *reinterpret_cast<const float4*>(xr + tid * 4);
  float s  = xv.x + xv.y + xv.z + xv.w;
  float ss = xv.x*xv.x + xv.y*xv.y + xv.z*xv.z + xv.w*xv.w;
  #pragma unroll
  for (int off = 32; off > 0; off >>= 1) {
    s  += __shfl_down(s, off, 64);
    ss += __shfl_down(ss, off, 64);
  }
  __shared__ float rs[4], rss[4];
  __shared__ float smu, srstd;
  if ((tid & 63) == 0) { rs[tid >> 6] = s; rss[tid >> 6] = ss; }
  __syncthreads();
  if (tid == 0) {
    float S  = rs[0] + rs[1] + rs[2] + rs[3];
    float SS = rss[0] + rss[1] + rss[2] + rss[3];
    float mu  = S * (1.0f / C_);
    float var = SS * (1.0f / C_) - mu * mu;
    smu = mu; srstd = rsqrtf(var + 1e-5f);
  }
  __syncthreads();
  const float mu = smu, rstd = srstd;
  float4 gv = *reinterpret_cast<const float4*>(g + tid * 4);
  float4 bv = *reinterpret_cast<const float4*>(b + tid * 4);
  union { unsigned long long ll; unsigned short s[4]; } o;
  o.s[0] = f2bf((xv.x - mu) * rstd * gv.x + bv.x);
  o.s[1] = f2bf((xv.y - mu) * rstd * gv.y + bv.y);
  o.s[2] = f2bf((xv.z - mu) * rstd * gv.z + bv.z);
  o.s[3] = f2bf((xv.w - mu) * rstd * gv.w + bv.w);
  *reinterpret_cast<unsigned long long*>(outb + (size_t)row * C_ + tid * 4) = o.ll;
}

// ---------------- Transpose + cast: fp32 [R][Cc] -> bf16 [Cc][R], batched ---
__global__ __launch_bounds__(256) void transpose_cast(
    const float* __restrict__ in, unsigned short* __restrict__ out, int R, int Cc)
{
  __shared__ float tile[32][33];
  const int bz = blockIdx.z;
  in  += (size_t)bz * R * Cc;
  out += (size_t)bz * R * Cc;
  const int tx = threadIdx.x & 31;
  const int ty = threadIdx.x >> 5;    // 0..7
  const int c0 = blockIdx.x * 32, r0 = blockIdx.y * 32;
  #pragma unroll
  for (int j = 0; j < 4; ++j)
    tile[ty + j*8][tx] = in[(size_t)(r0 + ty + j*8) * Cc + c0 + tx];
  __syncthreads();
  #pragma unroll
  for (int j = 0; j < 4; ++j)
    out[(size_t)(c0 + ty + j*8) * R + r0 + tx] = f2bf(tile[tx][ty + j*8]);
}

// ---------------- bf16 MFMA GEMM (m97 structure) ----------------
template<bool OUTBF16, bool RELU, bool HASB, bool HASRES>
__global__ __launch_bounds__(256) void gemm_bf16(
    const unsigned short* __restrict__ A,   // [M][K] bf16
    const unsigned short* __restrict__ Bt,  // [N][K] bf16
    const float* __restrict__ bias,         // [N] fp32
    const unsigned short* __restrict__ res, // [M][N] bf16
    void* __restrict__ Cout,                // [M][N] fp32 or bf16
    int M, int N, int K)
{
  __shared__ unsigned short As[128 * 32];
  __shared__ unsigned short Bs[128 * 32];
  const int tid  = threadIdx.x;
  const int lane = tid & 63;
  const int wave = tid >> 6;
  const int wm = wave & 1, wn = wave >> 1;
  const int m0 = blockIdx.x * 128, n0 = blockIdx.y * 128;

  const int lrow = lane >> 2;
  const int lcol = (lane & 3) * 8;
  const int fr = lane & 15;
  const int fq = lane >> 4;

  floatx4 acc[4][4] = {};

  const unsigned short* Aw = A  + (size_t)m0 * K;
  const unsigned short* Bw = Bt + (size_t)n0 * K;

  for (int k0 = 0; k0 < K; k0 += 32) {
    __syncthreads();
    #pragma unroll
    for (int i = 0; i < 2; ++i) {
      const int rbase = i * 64 + wave * 16;
      const unsigned short* gp = Aw + (size_t)(rbase + lrow) * K + k0 + lcol;
      __builtin_amdgcn_global_load_lds(
          (const __attribute__((address_space(1))) void*)gp,
          (__attribute__((address_space(3))) void*)(As + rbase * 32),
          16, 0, 0);
    }
    #pragma unroll
    for (int i = 0; i < 2; ++i) {
      const int rbase = i * 64 + wave * 16;
      const unsigned short* gp = Bw + (size_t)(rbase + lrow) * K + k0 + lcol;
      __builtin_amdgcn_global_load_lds(
          (const __attribute__((address_space(1))) void*)gp,
          (__attribute__((address_space(3))) void*)(Bs + rbase * 32),
          16, 0, 0);
    }
    __syncthreads();

    bf16x8 af[4], bfr[4];
    #pragma unroll
    for (int t = 0; t < 4; ++t) {
      af[t]  = *reinterpret_cast<const bf16x8*>(As + (wm*64 + t*16 + fr)*32 + fq*8);
      bfr[t] = *reinterpret_cast<const bf16x8*>(Bs + (wn*64 + t*16 + fr)*32 + fq*8);
    }
    #pragma unroll
    for (int mt = 0; mt < 4; ++mt)
      #pragma unroll
      for (int nt = 0; nt < 4; ++nt)
        acc[mt][nt] = __builtin_amdgcn_mfma_f32_16x16x32_bf16(
            af[mt], bfr[nt], acc[mt][nt], 0, 0, 0);
  }

  #pragma unroll
  for (int nt = 0; nt < 4; ++nt) {
    const int col = n0 + wn*64 + nt*16 + fr;
    const float bv = HASB ? bias[col] : 0.0f;
    #pragma unroll
    for (int mt = 0; mt < 4; ++mt) {
      #pragma unroll
      for (int r = 0; r < 4; ++r) {
        const int row = m0 + wm*64 + mt*16 + fq*4 + r;
        float v = acc[mt][nt][r] + bv;
        if (RELU) v = v > 0.0f ? v : 0.0f;
        if (HASRES) v += bf2f(res[(size_t)row * N + col]);
        if (OUTBF16) ((unsigned short*)Cout)[(size_t)row * N + col] = f2bf(v);
        else         ((float*)Cout)[(size_t)row * N + col] = v;
      }
    }
  }
}

// ---------------- V transpose: qkv V-part -> vt[bh][64 d][2048 t] bf16 -----
__global__ __launch_bounds__(256) void v_transpose(
    const unsigned short* __restrict__ qkv, unsigned short* __restrict__ vt)
{
  __shared__ __align__(16) unsigned short sT[64][72];
  const int st = blockIdx.x;        // s-tile of 64
  const int bh = blockIdx.y;
  const int b = bh >> 4, h = bh & 15;
  const int t = threadIdx.x;
  const int r = t >> 2, c0 = (t & 3) * 16;
  const unsigned short* src =
      qkv + (size_t)(b * T_ + st * 64 + r) * 3072 + 2048 + h * 64 + c0;
  *(u16x8*)&sT[r][c0]     = *(const u16x8*)src;
  *(u16x8*)&sT[r][c0 + 8] = *(const u16x8*)(src + 8);
  __syncthreads();
  const int d = t >> 2, sc = (t & 3) * 16;
  unsigned short v[16];
  #pragma unroll
  for (int j = 0; j < 16; ++j) v[j] = sT[sc + j][d];
  unsigned short* dst = vt + ((size_t)bh * 64 + d) * (size_t)T_ + st * 64 + sc;
  *(uint4*)dst       = *(uint4*)&v[0];
  *(uint4*)(dst + 8) = *(uint4*)&v[8];
}

// ---------------- MFMA flash attention v2 (S^T form) ----------------
// qkv bf16 [B*T][3072] (q|k|v), vt bf16 [32 bh][64 d][2048 t].
// Block: 256 thr = 4 waves; Q-tile 64 (16 rows/wave); K-tile 64.
// S^T = K·Q^T puts each lane on a fixed q column (q = t0+w*16+lane&15) with
// 4 consecutive s per reg -> softmax = in-lane reduce + 2 shfl_xor; P stored
// s-contiguous with one ds_write_b64 per 16x16 tile; sP rows are wave-private
// so no barrier between softmax and PV.
__global__ __launch_bounds__(256, 4) void attn_mfma(
    const unsigned short* __restrict__ qkv,
    const unsigned short* __restrict__ vt,
    unsigned short* __restrict__ out)
{
  const int bh = blockIdx.x;
  const int qt = (int)(gridDim.y - 1) - (int)blockIdx.y;  // long blocks first
  const int b = bh >> 4, h = bh & 15;
  const int tid = threadIdx.x;
  const int w = tid >> 6;
  const int lane = tid & 63;
  const int l15 = lane & 15, fq = lane >> 4;
  const int t0 = qt * 64;
  const int q_row = t0 + w * 16 + l15;   // this lane's q column

  __shared__ __align__(16) unsigned short sK [64][72];
  __shared__ __align__(16) unsigned short sVt[64][72];
  __shared__ __align__(16) unsigned short sP [64][72];

  // Q fragment (dual-use A/B layout): Q[q_row][d = c*32 + fq*8 + j]
  bf16x8 aq[2];
  {
    const unsigned short* qp = qkv + (size_t)(b*T_ + q_row)*3072 + h*HS_ + fq*8;
    aq[0] = *(const bf16x8*)qp;
    aq[1] = *(const bf16x8*)(qp + 32);
  }

  floatx4 oacc[4] = {};   // [dt]; C/D: col d = dt*16+l15, row q-local = fq*4+r
  float m_s = -3.0e38f, l_s = 0.0f;
  const float c1 = 1.4426950408889634f / 32.0f;   // log2(e) * C^-0.5
  const int nks = qt + 1;

  for (int ks = 0; ks < nks; ++ks) {
    __syncthreads();   // everyone done reading sK/sVt from previous iter
    {   // stage K tile [s][d] and Vt tile [d][s]
      const int r = tid >> 2, c0 = (tid & 3) * 16;
      const unsigned short* kp =
          qkv + (size_t)(b*T_ + ks*64 + r)*3072 + C_ + h*HS_ + c0;
      u16x8 k0 = *(const u16x8*)kp, k1 = *(const u16x8*)(kp + 8);
      const unsigned short* vp =
          vt + ((size_t)bh*64 + r)*(size_t)T_ + ks*64 + c0;
      u16x8 v0 = *(const u16x8*)vp, v1 = *(const u16x8*)(vp + 8);
      *(u16x8*)&sK[r][c0]      = k0; *(u16x8*)&sK[r][c0 + 8]  = k1;
      *(u16x8*)&sVt[r][c0]     = v0; *(u16x8*)&sVt[r][c0 + 8] = v1;
    }
    __syncthreads();

    // S^T[st] = K-tile · Q^T : D[m = s-local = fq*4+r][n = q-local = l15]
    floatx4 stacc[4] = {};
    #pragma unroll
    for (int st = 0; st < 4; ++st) {
      bf16x8 k0 = *(const bf16x8*)&sK[st*16 + l15][fq*8];
      bf16x8 k1 = *(const bf16x8*)&sK[st*16 + l15][32 + fq*8];
      stacc[st] = __builtin_amdgcn_mfma_f32_16x16x32_bf16(k0, aq[0], stacc[st], 0, 0, 0);
      stacc[st] = __builtin_amdgcn_mfma_f32_16x16x32_bf16(k1, aq[1], stacc[st], 0, 0, 0);
    }

    if (ks == qt) {   // diagonal tile: mask s > q
      #pragma unroll
      for (int st = 0; st < 4; ++st)
        #pragma unroll
        for (int r = 0; r < 4; ++r) {
          const int s = ks*64 + st*16 + fq*4 + r;
          if (s > q_row) stacc[st][r] = -3.0e38f;
        }
    }

    // online softmax over s for this lane's q: in-lane 16 + 2 shfl_xor
    float mx = -3.0e38f;
    #pragma unroll
    for (int st = 0; st < 4; ++st)
      #pragma unroll
      for (int r = 0; r < 4; ++r) mx = fmaxf(mx, stacc[st][r]);
    mx = fmaxf(mx, __shfl_xor(mx, 16, 64));
    mx = fmaxf(mx, __shfl_xor(mx, 32, 64));
    const float mnew = fmaxf(m_s, mx);
    const float alpha = exp2f((m_s - mnew) * c1);
    m_s = mnew;

    float sum = 0.0f;
    #pragma unroll
    for (int st = 0; st < 4; ++st) {
      unsigned pu[4];
      #pragma unroll
      for (int r = 0; r < 4; ++r) {
        const float p = exp2f((stacc[st][r] - mnew) * c1);
        sum += p;
        union { float f; unsigned u; } cv; cv.f = p;
        pu[r] = cv.u + 0x8000u;              // round-half-up to bf16
      }
      const unsigned lo = __builtin_amdgcn_perm(pu[1], pu[0], 0x07060302u);
      const unsigned hi = __builtin_amdgcn_perm(pu[3], pu[2], 0x07060302u);
      const unsigned long long pk = ((unsigned long long)hi << 32) | lo;
      // P[q][s]: row = wave-private q, col = 4 consecutive s
      *(unsigned long long*)&sP[w*16 + l15][st*16 + fq*4] = pk;
    }
    sum += __shfl_xor(sum, 16, 64);
    sum += __shfl_xor(sum, 32, 64);
    l_s = l_s * alpha + sum;

    // rescale O rows (alpha lives at lane l15 == q-local; O row = fq*4+r)
    #pragma unroll
    for (int r = 0; r < 4; ++r) {
      const float ar = __shfl(alpha, fq*4 + r, 64);
      #pragma unroll
      for (int dt = 0; dt < 4; ++dt) oacc[dt][r] *= ar;
    }

    // PV: O[q][d] += P[q][s] · V[s][d]   (sP rows are wave-private: no barrier)
    #pragma unroll
    for (int c = 0; c < 2; ++c) {
      bf16x8 ap = *(const bf16x8*)&sP[w*16 + l15][c*32 + fq*8];
      #pragma unroll
      for (int dt = 0; dt < 4; ++dt) {
        bf16x8 bv = *(const bf16x8*)&sVt[dt*16 + l15][c*32 + fq*8];
        oacc[dt] = __builtin_amdgcn_mfma_f32_16x16x32_bf16(ap, bv, oacc[dt], 0, 0, 0);
      }
    }
  }

  // epilogue: O /= l, write bf16 [token][h*64 + d]
  #pragma unroll
  for (int r = 0; r < 4; ++r) {
    const float il = 1.0f / __shfl(l_s, fq*4 + r, 64);
    const int q = t0 + w*16 + fq*4 + r;
    #pragma unroll
    for (int dt = 0; dt < 4; ++dt)
      out[(size_t)(b*T_ + q)*C_ + h*HS_ + dt*16 + l15] = f2bf(oacc[dt][r] * il);
  }
}

extern "C" void kernel_launch(void* const* d_in, const int* in_sizes, int n_in,
                              void* d_out, int out_size, void* d_ws, size_t ws_size,
                              hipStream_t stream)
{
  const float* x   = (const float*)d_in[0];
  const float* Wq  = (const float*)d_in[1];
  const float* Wk  = (const float*)d_in[2];
  const float* Wv  = (const float*)d_in[3];
  const float* Wo  = (const float*)d_in[4];
  const float* bo  = (const float*)d_in[5];
  const float* W1  = (const float*)d_in[6];
  const float* b1  = (const float*)d_in[7];
  const float* W2  = (const float*)d_in[8];
  const float* b2  = (const float*)d_in[9];
  const float* g1  = (const float*)d_in[10];
  const float* be1 = (const float*)d_in[11];
  const float* g2  = (const float*)d_in[12];
  const float* be2 = (const float*)d_in[13];
  float* out = (float*)d_out;

  // Workspace (72 MB peak, liveness-based reuse):
  char* ws = (char*)d_ws;
  unsigned short* BtQKV = (unsigned short*)(ws + (size_t) 0*MB);  // 6MB
  unsigned short* BtWo  = (unsigned short*)(ws + (size_t) 6*MB);  // 2MB
  unsigned short* BtW1  = (unsigned short*)(ws + (size_t) 8*MB);  // 8MB
  unsigned short* BtW2  = (unsigned short*)(ws + (size_t)16*MB);  // 8MB
  unsigned short* lnb   = (unsigned short*)(ws + (size_t)24*MB);  // 8MB
  unsigned short* qkvb  = (unsigned short*)(ws + (size_t)32*MB);  // [4096][3072] 24MB
  unsigned short* vtb   = (unsigned short*)(ws + (size_t)56*MB);  // [32][64][2048] 8MB
  unsigned short* attnb = (unsigned short*)(ws + (size_t)64*MB);  // 8MB
  float*          x2    = (float*)         (ws + (size_t)32*MB);  // 16MB (qkv dead)
  unsigned short* hb    = (unsigned short*)(ws + (size_t)32*MB);  // 32MB (x2,vt dead)

  dim3 blk(256);

  transpose_cast<<<dim3(HS_/32, C_/32, H_), blk, 0, stream>>>(Wq, BtQKV,               C_, HS_);
  transpose_cast<<<dim3(HS_/32, C_/32, H_), blk, 0, stream>>>(Wk, BtQKV + 1024*1024,   C_, HS_);
  transpose_cast<<<dim3(HS_/32, C_/32, H_), blk, 0, stream>>>(Wv, BtQKV + 2*1024*1024, C_, HS_);
  transpose_cast<<<dim3(C_/32,  C_/32, 1),  blk, 0, stream>>>(Wo, BtWo, C_, C_);
  transpose_cast<<<dim3(4*C_/32,C_/32, 1),  blk, 0, stream>>>(W1, BtW1, C_, 4*C_);
  transpose_cast<<<dim3(C_/32,4*C_/32, 1),  blk, 0, stream>>>(W2, BtW2, 4*C_, C_);

  ln_kernel<<<dim3(N_ROWS), blk, 0, stream>>>(x, g1, be1, lnb);

  // Fused QKV GEMM -> bf16 [4096][3072]
  gemm_bf16<true,false,false,false><<<dim3(N_ROWS/128, 3072/128), blk, 0, stream>>>(
      lnb, BtQKV, nullptr, nullptr, qkvb, N_ROWS, 3072, C_);

  // V transpose -> vt[bh][d][t]
  v_transpose<<<dim3(T_/64, B_*H_), blk, 0, stream>>>(qkvb, vtb);

  // MFMA flash attention -> bf16 attnb  (Q-tile 64: 32 bh x 32 qt = 1024 blocks)
  attn_mfma<<<dim3(B_*H_, T_/64), blk, 0, stream>>>(qkvb, vtb, attnb);

  // Wo GEMM + bias + residual(ln1) -> fp32 x2
  gemm_bf16<false,false,true,true><<<dim3(N_ROWS/128, C_/128), blk, 0, stream>>>(
      attnb, BtWo, bo, lnb, x2, N_ROWS, C_, C_);

  // LN2
  ln_kernel<<<dim3(N_ROWS), blk, 0, stream>>>(x2, g2, be2, lnb);

  // W1 GEMM + bias + ReLU -> bf16 hb
  gemm_bf16<true,true,true,false><<<dim3(N_ROWS/128, 4*C_/128), blk, 0, stream>>>(
      lnb, BtW1, b1, nullptr, hb, N_ROWS, 4*C_, C_);

  // W2 GEMM + bias + residual(ln2) -> fp32 out
  gemm_bf16<false,false,true,true><<<dim3(N_ROWS/128, C_/128), blk, 0, stream>>>(
      hb, BtW2, b2, lnb, out, N_ROWS, C_, 4*C_);
}

// Round 7
// 391.528 us; speedup vs baseline: 5.6219x; 1.0452x over previous
//
#include <hip/hip_runtime.h>
#include <hip/hip_bf16.h>
#include <math.h>

#define B_ 2
#define T_ 2048
#define C_ 1024
#define H_ 16
#define HS_ 64
#define N_ROWS (B_*T_)   // 4096
#define MB (1024*1024)

typedef __attribute__((ext_vector_type(8))) short bf16x8;
typedef __attribute__((ext_vector_type(8))) unsigned short u16x8;
typedef __attribute__((ext_vector_type(4))) float floatx4;

static __device__ __forceinline__ unsigned short f2bf(float f) {
  union { float f; unsigned u; } v; v.f = f;
  unsigned r = v.u + 0x7fff + ((v.u >> 16) & 1);   // round-to-nearest-even
  return (unsigned short)(r >> 16);
}
static __device__ __forceinline__ float bf2f(unsigned short s) {
  union { unsigned u; float f; } v; v.u = ((unsigned)s) << 16;
  return v.f;
}

// ---------------- LayerNorm: one block per row, bf16 output ----------------
__global__ __launch_bounds__(256) void ln_kernel(
    const float* __restrict__ x, const float* __restrict__ g,
    const float* __restrict__ b, unsigned short* __restrict__ outb)
{
  const int row = blockIdx.x;
  const int tid = threadIdx.x;
  const float* xr = x + (size_t)row * C_;
  float4 xv = *reinterpret_cast<const float4*>(xr + tid * 4);
  float s  = xv.x + xv.y + xv.z + xv.w;
  float ss = xv.x*xv.x + xv.y*xv.y + xv.z*xv.z + xv.w*xv.w;
  #pragma unroll
  for (int off = 32; off > 0; off >>= 1) {
    s  += __shfl_down(s, off, 64);
    ss += __shfl_down(ss, off, 64);
  }
  __shared__ float rs[4], rss[4];
  __shared__ float smu, srstd;
  if ((tid & 63) == 0) { rs[tid >> 6] = s; rss[tid >> 6] = ss; }
  __syncthreads();
  if (tid == 0) {
    float S  = rs[0] + rs[1] + rs[2] + rs[3];
    float SS = rss[0] + rss[1] + rss[2] + rss[3];
    float mu  = S * (1.0f / C_);
    float var = SS * (1.0f / C_) - mu * mu;
    smu = mu; srstd = rsqrtf(var + 1e-5f);
  }
  __syncthreads();
  const float mu = smu, rstd = srstd;
  float4 gv = *reinterpret_cast<const float4*>(g + tid * 4);
  float4 bv = *reinterpret_cast<const float4*>(b + tid * 4);
  union { unsigned long long ll; unsigned short s[4]; } o;
  o.s[0] = f2bf((xv.x - mu) * rstd * gv.x + bv.x);
  o.s[1] = f2bf((xv.y - mu) * rstd * gv.y + bv.y);
  o.s[2] = f2bf((xv.z - mu) * rstd * gv.z + bv.z);
  o.s[3] = f2bf((xv.w - mu) * rstd * gv.w + bv.w);
  *reinterpret_cast<unsigned long long*>(outb + (size_t)row * C_ + tid * 4) = o.ll;
}

// ---------------- Transpose + cast: fp32 [R][Cc] -> bf16 [Cc][R], batched ---
__global__ __launch_bounds__(256) void transpose_cast(
    const float* __restrict__ in, unsigned short* __restrict__ out, int R, int Cc)
{
  __shared__ float tile[32][33];
  const int bz = blockIdx.z;
  in  += (size_t)bz * R * Cc;
  out += (size_t)bz * R * Cc;
  const int tx = threadIdx.x & 31;
  const int ty = threadIdx.x >> 5;    // 0..7
  const int c0 = blockIdx.x * 32, r0 = blockIdx.y * 32;
  #pragma unroll
  for (int j = 0; j < 4; ++j)
    tile[ty + j*8][tx] = in[(size_t)(r0 + ty + j*8) * Cc + c0 + tx];
  __syncthreads();
  #pragma unroll
  for (int j = 0; j < 4; ++j)
    out[(size_t)(c0 + ty + j*8) * R + r0 + tx] = f2bf(tile[tx][ty + j*8]);
}

// ---------------- bf16 MFMA GEMM (m97 structure) ----------------
// TNB = 128: 4 waves 2x2, wave-tile 64x64 (acc 4x4). Grid-starved shapes use
// TNB = 64: 4 waves 2x2, wave-tile 64x32 (acc 4x2) -> 2x the block count.
template<int TNB, bool OUTBF16, bool RELU, bool HASB, bool HASRES>
__global__ __launch_bounds__(256) void gemm_bf16(
    const unsigned short* __restrict__ A,   // [M][K] bf16
    const unsigned short* __restrict__ Bt,  // [N][K] bf16
    const float* __restrict__ bias,         // [N] fp32
    const unsigned short* __restrict__ res, // [M][N] bf16
    void* __restrict__ Cout,                // [M][N] fp32 or bf16
    int M, int N, int K)
{
  constexpr int NT = TNB / 32;              // B-tiles per wave: 4 or 2
  constexpr int WN = TNB / 2;               // wave n-extent: 64 or 32
  __shared__ unsigned short As[128 * 32];
  __shared__ unsigned short Bs[TNB * 32];
  const int tid  = threadIdx.x;
  const int lane = tid & 63;
  const int wave = tid >> 6;
  const int wm = wave & 1, wn = wave >> 1;
  const int m0 = blockIdx.x * 128, n0 = blockIdx.y * TNB;

  const int lrow = lane >> 2;
  const int lcol = (lane & 3) * 8;
  const int fr = lane & 15;
  const int fq = lane >> 4;

  floatx4 acc[4][NT] = {};

  const unsigned short* Aw = A  + (size_t)m0 * K;
  const unsigned short* Bw = Bt + (size_t)n0 * K;

  for (int k0 = 0; k0 < K; k0 += 32) {
    __syncthreads();
    #pragma unroll
    for (int i = 0; i < 2; ++i) {
      const int rbase = i * 64 + wave * 16;
      const unsigned short* gp = Aw + (size_t)(rbase + lrow) * K + k0 + lcol;
      __builtin_amdgcn_global_load_lds(
          (const __attribute__((address_space(1))) void*)gp,
          (__attribute__((address_space(3))) void*)(As + rbase * 32),
          16, 0, 0);
    }
    #pragma unroll
    for (int i = 0; i < TNB / 64; ++i) {
      const int rbase = i * 64 + wave * 16;
      const unsigned short* gp = Bw + (size_t)(rbase + lrow) * K + k0 + lcol;
      __builtin_amdgcn_global_load_lds(
          (const __attribute__((address_space(1))) void*)gp,
          (__attribute__((address_space(3))) void*)(Bs + rbase * 32),
          16, 0, 0);
    }
    __syncthreads();

    bf16x8 af[4], bfr[NT];
    #pragma unroll
    for (int t = 0; t < 4; ++t)
      af[t]  = *reinterpret_cast<const bf16x8*>(As + (wm*64 + t*16 + fr)*32 + fq*8);
    #pragma unroll
    for (int t = 0; t < NT; ++t)
      bfr[t] = *reinterpret_cast<const bf16x8*>(Bs + (wn*WN + t*16 + fr)*32 + fq*8);
    #pragma unroll
    for (int mt = 0; mt < 4; ++mt)
      #pragma unroll
      for (int nt = 0; nt < NT; ++nt)
        acc[mt][nt] = __builtin_amdgcn_mfma_f32_16x16x32_bf16(
            af[mt], bfr[nt], acc[mt][nt], 0, 0, 0);
  }

  #pragma unroll
  for (int nt = 0; nt < NT; ++nt) {
    const int col = n0 + wn*WN + nt*16 + fr;
    const float bv = HASB ? bias[col] : 0.0f;
    #pragma unroll
    for (int mt = 0; mt < 4; ++mt) {
      #pragma unroll
      for (int r = 0; r < 4; ++r) {
        const int row = m0 + wm*64 + mt*16 + fq*4 + r;
        float v = acc[mt][nt][r] + bv;
        if (RELU) v = v > 0.0f ? v : 0.0f;
        if (HASRES) v += bf2f(res[(size_t)row * N + col]);
        if (OUTBF16) ((unsigned short*)Cout)[(size_t)row * N + col] = f2bf(v);
        else         ((float*)Cout)[(size_t)row * N + col] = v;
      }
    }
  }
}

// ---------------- V transpose: qkv V-part -> vt[bh][64 d][2048 t] bf16 -----
__global__ __launch_bounds__(256) void v_transpose(
    const unsigned short* __restrict__ qkv, unsigned short* __restrict__ vt)
{
  __shared__ __align__(16) unsigned short sT[64][72];
  const int st = blockIdx.x;        // s-tile of 64
  const int bh = blockIdx.y;
  const int b = bh >> 4, h = bh & 15;
  const int t = threadIdx.x;
  const int r = t >> 2, c0 = (t & 3) * 16;
  const unsigned short* src =
      qkv + (size_t)(b * T_ + st * 64 + r) * 3072 + 2048 + h * 64 + c0;
  *(u16x8*)&sT[r][c0]     = *(const u16x8*)src;
  *(u16x8*)&sT[r][c0 + 8] = *(const u16x8*)(src + 8);
  __syncthreads();
  const int d = t >> 2, sc = (t & 3) * 16;
  unsigned short v[16];
  #pragma unroll
  for (int j = 0; j < 16; ++j) v[j] = sT[sc + j][d];
  unsigned short* dst = vt + ((size_t)bh * 64 + d) * (size_t)T_ + st * 64 + sc;
  *(uint4*)dst       = *(uint4*)&v[0];
  *(uint4*)(dst + 8) = *(uint4*)&v[8];
}

// ---------------- MFMA flash attention v2 (S^T form) ----------------
__global__ __launch_bounds__(256, 4) void attn_mfma(
    const unsigned short* __restrict__ qkv,
    const unsigned short* __restrict__ vt,
    unsigned short* __restrict__ out)
{
  const int bh = blockIdx.x;
  const int qt = (int)(gridDim.y - 1) - (int)blockIdx.y;  // long blocks first
  const int b = bh >> 4, h = bh & 15;
  const int tid = threadIdx.x;
  const int w = tid >> 6;
  const int lane = tid & 63;
  const int l15 = lane & 15, fq = lane >> 4;
  const int t0 = qt * 64;
  const int q_row = t0 + w * 16 + l15;   // this lane's q column

  __shared__ __align__(16) unsigned short sK [64][72];
  __shared__ __align__(16) unsigned short sVt[64][72];
  __shared__ __align__(16) unsigned short sP [64][72];

  // Q fragment (dual-use A/B layout): Q[q_row][d = c*32 + fq*8 + j]
  bf16x8 aq[2];
  {
    const unsigned short* qp = qkv + (size_t)(b*T_ + q_row)*3072 + h*HS_ + fq*8;
    aq[0] = *(const bf16x8*)qp;
    aq[1] = *(const bf16x8*)(qp + 32);
  }

  floatx4 oacc[4] = {};   // [dt]; C/D: col d = dt*16+l15, row q-local = fq*4+r
  float m_s = -3.0e38f, l_s = 0.0f;
  const float c1 = 1.4426950408889634f / 32.0f;   // log2(e) * C^-0.5
  const int nks = qt + 1;

  for (int ks = 0; ks < nks; ++ks) {
    __syncthreads();   // everyone done reading sK/sVt from previous iter
    {   // stage K tile [s][d] and Vt tile [d][s]
      const int r = tid >> 2, c0 = (tid & 3) * 16;
      const unsigned short* kp =
          qkv + (size_t)(b*T_ + ks*64 + r)*3072 + C_ + h*HS_ + c0;
      u16x8 k0 = *(const u16x8*)kp, k1 = *(const u16x8*)(kp + 8);
      const unsigned short* vp =
          vt + ((size_t)bh*64 + r)*(size_t)T_ + ks*64 + c0;
      u16x8 v0 = *(const u16x8*)vp, v1 = *(const u16x8*)(vp + 8);
      *(u16x8*)&sK[r][c0]      = k0; *(u16x8*)&sK[r][c0 + 8]  = k1;
      *(u16x8*)&sVt[r][c0]     = v0; *(u16x8*)&sVt[r][c0 + 8] = v1;
    }
    __syncthreads();

    // S^T[st] = K-tile · Q^T : D[m = s-local = fq*4+r][n = q-local = l15]
    floatx4 stacc[4] = {};
    #pragma unroll
    for (int st = 0; st < 4; ++st) {
      bf16x8 k0 = *(const bf16x8*)&sK[st*16 + l15][fq*8];
      bf16x8 k1 = *(const bf16x8*)&sK[st*16 + l15][32 + fq*8];
      stacc[st] = __builtin_amdgcn_mfma_f32_16x16x32_bf16(k0, aq[0], stacc[st], 0, 0, 0);
      stacc[st] = __builtin_amdgcn_mfma_f32_16x16x32_bf16(k1, aq[1], stacc[st], 0, 0, 0);
    }

    if (ks == qt) {   // diagonal tile: mask s > q
      #pragma unroll
      for (int st = 0; st < 4; ++st)
        #pragma unroll
        for (int r = 0; r < 4; ++r) {
          const int s = ks*64 + st*16 + fq*4 + r;
          if (s > q_row) stacc[st][r] = -3.0e38f;
        }
    }

    // online softmax over s for this lane's q: in-lane 16 + 2 shfl_xor
    float mx = -3.0e38f;
    #pragma unroll
    for (int st = 0; st < 4; ++st)
      #pragma unroll
      for (int r = 0; r < 4; ++r) mx = fmaxf(mx, stacc[st][r]);
    mx = fmaxf(mx, __shfl_xor(mx, 16, 64));
    mx = fmaxf(mx, __shfl_xor(mx, 32, 64));
    const float mnew = fmaxf(m_s, mx);
    const float alpha = exp2f((m_s - mnew) * c1);
    m_s = mnew;

    float sum = 0.0f;
    #pragma unroll
    for (int st = 0; st < 4; ++st) {
      unsigned pu[4];
      #pragma unroll
      for (int r = 0; r < 4; ++r) {
        const float p = exp2f((stacc[st][r] - mnew) * c1);
        sum += p;
        union { float f; unsigned u; } cv; cv.f = p;
        pu[r] = cv.u + 0x8000u;              // round-half-up to bf16
      }
      const unsigned lo = __builtin_amdgcn_perm(pu[1], pu[0], 0x07060302u);
      const unsigned hi = __builtin_amdgcn_perm(pu[3], pu[2], 0x07060302u);
      const unsigned long long pk = ((unsigned long long)hi << 32) | lo;
      // P[q][s]: row = wave-private q, col = 4 consecutive s
      *(unsigned long long*)&sP[w*16 + l15][st*16 + fq*4] = pk;
    }
    sum += __shfl_xor(sum, 16, 64);
    sum += __shfl_xor(sum, 32, 64);
    l_s = l_s * alpha + sum;

    // rescale O rows (alpha lives at lane l15 == q-local; O row = fq*4+r)
    #pragma unroll
    for (int r = 0; r < 4; ++r) {
      const float ar = __shfl(alpha, fq*4 + r, 64);
      #pragma unroll
      for (int dt = 0; dt < 4; ++dt) oacc[dt][r] *= ar;
    }

    // PV: O[q][d] += P[q][s] · V[s][d]   (sP rows are wave-private: no barrier)
    #pragma unroll
    for (int c = 0; c < 2; ++c) {
      bf16x8 ap = *(const bf16x8*)&sP[w*16 + l15][c*32 + fq*8];
      #pragma unroll
      for (int dt = 0; dt < 4; ++dt) {
        bf16x8 bv = *(const bf16x8*)&sVt[dt*16 + l15][c*32 + fq*8];
        oacc[dt] = __builtin_amdgcn_mfma_f32_16x16x32_bf16(ap, bv, oacc[dt], 0, 0, 0);
      }
    }
  }

  // epilogue: O /= l, write bf16 [token][h*64 + d]
  #pragma unroll
  for (int r = 0; r < 4; ++r) {
    const float il = 1.0f / __shfl(l_s, fq*4 + r, 64);
    const int q = t0 + w*16 + fq*4 + r;
    #pragma unroll
    for (int dt = 0; dt < 4; ++dt)
      out[(size_t)(b*T_ + q)*C_ + h*HS_ + dt*16 + l15] = f2bf(oacc[dt][r] * il);
  }
}

extern "C" void kernel_launch(void* const* d_in, const int* in_sizes, int n_in,
                              void* d_out, int out_size, void* d_ws, size_t ws_size,
                              hipStream_t stream)
{
  const float* x   = (const float*)d_in[0];
  const float* Wq  = (const float*)d_in[1];
  const float* Wk  = (const float*)d_in[2];
  const float* Wv  = (const float*)d_in[3];
  const float* Wo  = (const float*)d_in[4];
  const float* bo  = (const float*)d_in[5];
  const float* W1  = (const float*)d_in[6];
  const float* b1  = (const float*)d_in[7];
  const float* W2  = (const float*)d_in[8];
  const float* b2  = (const float*)d_in[9];
  const float* g1  = (const float*)d_in[10];
  const float* be1 = (const float*)d_in[11];
  const float* g2  = (const float*)d_in[12];
  const float* be2 = (const float*)d_in[13];
  float* out = (float*)d_out;

  // Workspace (72 MB peak, liveness-based reuse):
  char* ws = (char*)d_ws;
  unsigned short* BtQKV = (unsigned short*)(ws + (size_t) 0*MB);  // 6MB
  unsigned short* BtWo  = (unsigned short*)(ws + (size_t) 6*MB);  // 2MB
  unsigned short* BtW1  = (unsigned short*)(ws + (size_t) 8*MB);  // 8MB
  unsigned short* BtW2  = (unsigned short*)(ws + (size_t)16*MB);  // 8MB
  unsigned short* lnb   = (unsigned short*)(ws + (size_t)24*MB);  // 8MB
  unsigned short* qkvb  = (unsigned short*)(ws + (size_t)32*MB);  // [4096][3072] 24MB
  unsigned short* vtb   = (unsigned short*)(ws + (size_t)56*MB);  // [32][64][2048] 8MB
  unsigned short* attnb = (unsigned short*)(ws + (size_t)64*MB);  // 8MB
  float*          x2    = (float*)         (ws + (size_t)32*MB);  // 16MB (qkv dead)
  unsigned short* hb    = (unsigned short*)(ws + (size_t)32*MB);  // 32MB (x2,vt dead)

  dim3 blk(256);

  transpose_cast<<<dim3(HS_/32, C_/32, H_), blk, 0, stream>>>(Wq, BtQKV,               C_, HS_);
  transpose_cast<<<dim3(HS_/32, C_/32, H_), blk, 0, stream>>>(Wk, BtQKV + 1024*1024,   C_, HS_);
  transpose_cast<<<dim3(HS_/32, C_/32, H_), blk, 0, stream>>>(Wv, BtQKV + 2*1024*1024, C_, HS_);
  transpose_cast<<<dim3(C_/32,  C_/32, 1),  blk, 0, stream>>>(Wo, BtWo, C_, C_);
  transpose_cast<<<dim3(4*C_/32,C_/32, 1),  blk, 0, stream>>>(W1, BtW1, C_, 4*C_);
  transpose_cast<<<dim3(C_/32,4*C_/32, 1),  blk, 0, stream>>>(W2, BtW2, 4*C_, C_);

  ln_kernel<<<dim3(N_ROWS), blk, 0, stream>>>(x, g1, be1, lnb);

  // Fused QKV GEMM -> bf16 [4096][3072]   (768 blocks)
  gemm_bf16<128,true,false,false,false><<<dim3(N_ROWS/128, 3072/128), blk, 0, stream>>>(
      lnb, BtQKV, nullptr, nullptr, qkvb, N_ROWS, 3072, C_);

  // V transpose -> vt[bh][d][t]
  v_transpose<<<dim3(T_/64, B_*H_), blk, 0, stream>>>(qkvb, vtb);

  // MFMA flash attention -> bf16 attnb  (32 bh x 32 qt = 1024 blocks)
  attn_mfma<<<dim3(B_*H_, T_/64), blk, 0, stream>>>(qkvb, vtb, attnb);

  // Wo GEMM + bias + residual(ln1) -> fp32 x2   (TN=64: 512 blocks, was 256)
  gemm_bf16<64,false,false,true,true><<<dim3(N_ROWS/128, C_/64), blk, 0, stream>>>(
      attnb, BtWo, bo, lnb, x2, N_ROWS, C_, C_);

  // LN2
  ln_kernel<<<dim3(N_ROWS), blk, 0, stream>>>(x2, g2, be2, lnb);

  // W1 GEMM + bias + ReLU -> bf16 hb   (1024 blocks)
  gemm_bf16<128,true,true,true,false><<<dim3(N_ROWS/128, 4*C_/128), blk, 0, stream>>>(
      lnb, BtW1, b1, nullptr, hb, N_ROWS, 4*C_, C_);

  // W2 GEMM + bias + residual(ln2) -> fp32 out   (TN=64: 512 blocks, was 256)
  gemm_bf16<64,false,false,true,true><<<dim3(N_ROWS/128, C_/64), blk, 0, stream>>>(
      hb, BtW2, b2, lnb, out, N_ROWS, C_, 4*C_);
}

// Round 9
// 382.084 us; speedup vs baseline: 5.7609x; 1.0247x over previous
//
#include <hip/hip_runtime.h>
#include <hip/hip_bf16.h>
#include <math.h>

#define B_ 2
#define T_ 2048
#define C_ 1024
#define H_ 16
#define HS_ 64
#define N_ROWS (B_*T_)   // 4096
#define MB (1024*1024)

typedef __attribute__((ext_vector_type(8))) short bf16x8;
typedef __attribute__((ext_vector_type(8))) unsigned short u16x8;
typedef __attribute__((ext_vector_type(4))) float floatx4;

static __device__ __forceinline__ unsigned short f2bf(float f) {
  union { float f; unsigned u; } v; v.f = f;
  unsigned r = v.u + 0x7fff + ((v.u >> 16) & 1);   // round-to-nearest-even
  return (unsigned short)(r >> 16);
}
static __device__ __forceinline__ float bf2f(unsigned short s) {
  union { unsigned u; float f; } v; v.u = ((unsigned)s) << 16;
  return v.f;
}

// ---------------- LayerNorm: one block per row, bf16 output ----------------
__global__ __launch_bounds__(256) void ln_kernel(
    const float* __restrict__ x, const float* __restrict__ g,
    const float* __restrict__ b, unsigned short* __restrict__ outb)
{
  const int row = blockIdx.x;
  const int tid = threadIdx.x;
  const float* xr = x + (size_t)row * C_;
  float4 xv = *reinterpret_cast<const float4*>(xr + tid * 4);
  float s  = xv.x + xv.y + xv.z + xv.w;
  float ss = xv.x*xv.x + xv.y*xv.y + xv.z*xv.z + xv.w*xv.w;
  #pragma unroll
  for (int off = 32; off > 0; off >>= 1) {
    s  += __shfl_down(s, off, 64);
    ss += __shfl_down(ss, off, 64);
  }
  __shared__ float rs[4], rss[4];
  __shared__ float smu, srstd;
  if ((tid & 63) == 0) { rs[tid >> 6] = s; rss[tid >> 6] = ss; }
  __syncthreads();
  if (tid == 0) {
    float S  = rs[0] + rs[1] + rs[2] + rs[3];
    float SS = rss[0] + rss[1] + rss[2] + rss[3];
    float mu  = S * (1.0f / C_);
    float var = SS * (1.0f / C_) - mu * mu;
    smu = mu; srstd = rsqrtf(var + 1e-5f);
  }
  __syncthreads();
  const float mu = smu, rstd = srstd;
  float4 gv = *reinterpret_cast<const float4*>(g + tid * 4);
  float4 bv = *reinterpret_cast<const float4*>(b + tid * 4);
  union { unsigned long long ll; unsigned short s[4]; } o;
  o.s[0] = f2bf((xv.x - mu) * rstd * gv.x + bv.x);
  o.s[1] = f2bf((xv.y - mu) * rstd * gv.y + bv.y);
  o.s[2] = f2bf((xv.z - mu) * rstd * gv.z + bv.z);
  o.s[3] = f2bf((xv.w - mu) * rstd * gv.w + bv.w);
  *reinterpret_cast<unsigned long long*>(outb + (size_t)row * C_ + tid * 4) = o.ll;
}

// ---------------- Transpose + cast: fp32 [R][Cc] -> bf16 [Cc][R], batched ---
__global__ __launch_bounds__(256) void transpose_cast(
    const float* __restrict__ in, unsigned short* __restrict__ out, int R, int Cc)
{
  __shared__ float tile[32][33];
  const int bz = blockIdx.z;
  in  += (size_t)bz * R * Cc;
  out += (size_t)bz * R * Cc;
  const int tx = threadIdx.x & 31;
  const int ty = threadIdx.x >> 5;    // 0..7
  const int c0 = blockIdx.x * 32, r0 = blockIdx.y * 32;
  #pragma unroll
  for (int j = 0; j < 4; ++j)
    tile[ty + j*8][tx] = in[(size_t)(r0 + ty + j*8) * Cc + c0 + tx];
  __syncthreads();
  #pragma unroll
  for (int j = 0; j < 4; ++j)
    out[(size_t)(c0 + ty + j*8) * R + r0 + tx] = f2bf(tile[tx][ty + j*8]);
}

// ---------------- bf16 MFMA GEMM (m97 structure) ----------------
// TNB = 128: 4 waves 2x2, wave-tile 64x64 (acc 4x4). Grid-starved shapes use
// TNB = 64: 4 waves 2x2, wave-tile 64x32 (acc 4x2) -> 2x the block count.
template<int TNB, bool OUTBF16, bool RELU, bool HASB, bool HASRES>
__global__ __launch_bounds__(256) void gemm_bf16(
    const unsigned short* __restrict__ A,   // [M][K] bf16
    const unsigned short* __restrict__ Bt,  // [N][K] bf16
    const float* __restrict__ bias,         // [N] fp32
    const unsigned short* __restrict__ res, // [M][N] bf16
    void* __restrict__ Cout,                // [M][N] fp32 or bf16
    int M, int N, int K)
{
  constexpr int NT = TNB / 32;              // B-tiles per wave: 4 or 2
  constexpr int WN = TNB / 2;               // wave n-extent: 64 or 32
  __shared__ unsigned short As[128 * 32];
  __shared__ unsigned short Bs[TNB * 32];
  const int tid  = threadIdx.x;
  const int lane = tid & 63;
  const int wave = tid >> 6;
  const int wm = wave & 1, wn = wave >> 1;
  const int m0 = blockIdx.x * 128, n0 = blockIdx.y * TNB;

  const int lrow = lane >> 2;
  const int lcol = (lane & 3) * 8;
  const int fr = lane & 15;
  const int fq = lane >> 4;

  floatx4 acc[4][NT] = {};

  const unsigned short* Aw = A  + (size_t)m0 * K;
  const unsigned short* Bw = Bt + (size_t)n0 * K;

  for (int k0 = 0; k0 < K; k0 += 32) {
    __syncthreads();
    #pragma unroll
    for (int i = 0; i < 2; ++i) {
      const int rbase = i * 64 + wave * 16;
      const unsigned short* gp = Aw + (size_t)(rbase + lrow) * K + k0 + lcol;
      __builtin_amdgcn_global_load_lds(
          (const __attribute__((address_space(1))) void*)gp,
          (__attribute__((address_space(3))) void*)(As + rbase * 32),
          16, 0, 0);
    }
    #pragma unroll
    for (int i = 0; i < TNB / 64; ++i) {
      const int rbase = i * 64 + wave * 16;
      const unsigned short* gp = Bw + (size_t)(rbase + lrow) * K + k0 + lcol;
      __builtin_amdgcn_global_load_lds(
          (const __attribute__((address_space(1))) void*)gp,
          (__attribute__((address_space(3))) void*)(Bs + rbase * 32),
          16, 0, 0);
    }
    __syncthreads();

    bf16x8 af[4], bfr[NT];
    #pragma unroll
    for (int t = 0; t < 4; ++t)
      af[t]  = *reinterpret_cast<const bf16x8*>(As + (wm*64 + t*16 + fr)*32 + fq*8);
    #pragma unroll
    for (int t = 0; t < NT; ++t)
      bfr[t] = *reinterpret_cast<const bf16x8*>(Bs + (wn*WN + t*16 + fr)*32 + fq*8);
    #pragma unroll
    for (int mt = 0; mt < 4; ++mt)
      #pragma unroll
      for (int nt = 0; nt < NT; ++nt)
        acc[mt][nt] = __builtin_amdgcn_mfma_f32_16x16x32_bf16(
            af[mt], bfr[nt], acc[mt][nt], 0, 0, 0);
  }

  #pragma unroll
  for (int nt = 0; nt < NT; ++nt) {
    const int col = n0 + wn*WN + nt*16 + fr;
    const float bv = HASB ? bias[col] : 0.0f;
    #pragma unroll
    for (int mt = 0; mt < 4; ++mt) {
      #pragma unroll
      for (int r = 0; r < 4; ++r) {
        const int row = m0 + wm*64 + mt*16 + fq*4 + r;
        float v = acc[mt][nt][r] + bv;
        if (RELU) v = v > 0.0f ? v : 0.0f;
        if (HASRES) v += bf2f(res[(size_t)row * N + col]);
        if (OUTBF16) ((unsigned short*)Cout)[(size_t)row * N + col] = f2bf(v);
        else         ((float*)Cout)[(size_t)row * N + col] = v;
      }
    }
  }
}

// ---------------- split-K (2-way) bf16 GEMM -> fp32 partials ----------------
// blockIdx.z selects K-half; partials go to DISTINCT buffers C0 / C1
// (they are NOT contiguous in workspace — see liveness map in kernel_launch).
template<int TNB>
__global__ __launch_bounds__(256) void gemm_splitk(
    const unsigned short* __restrict__ A,   // [M][Kfull]
    const unsigned short* __restrict__ Bt,  // [N][Kfull]
    float* __restrict__ C0,                 // [M][N] fp32 (z=0)
    float* __restrict__ C1,                 // [M][N] fp32 (z=1)
    int M, int N, int Kfull)
{
  constexpr int NT = TNB / 32;
  constexpr int WN = TNB / 2;
  __shared__ unsigned short As[128 * 32];
  __shared__ unsigned short Bs[TNB * 32];
  const int tid  = threadIdx.x;
  const int lane = tid & 63;
  const int wave = tid >> 6;
  const int wm = wave & 1, wn = wave >> 1;
  const int m0 = blockIdx.x * 128, n0 = blockIdx.y * TNB;
  const int z  = blockIdx.z;
  const int Kh = Kfull >> 1;

  const int lrow = lane >> 2;
  const int lcol = (lane & 3) * 8;
  const int fr = lane & 15;
  const int fq = lane >> 4;

  floatx4 acc[4][NT] = {};

  const unsigned short* Aw = A  + (size_t)m0 * Kfull + (size_t)z * Kh;
  const unsigned short* Bw = Bt + (size_t)n0 * Kfull + (size_t)z * Kh;
  float* Cw = z ? C1 : C0;

  for (int k0 = 0; k0 < Kh; k0 += 32) {
    __syncthreads();
    #pragma unroll
    for (int i = 0; i < 2; ++i) {
      const int rbase = i * 64 + wave * 16;
      const unsigned short* gp = Aw + (size_t)(rbase + lrow) * Kfull + k0 + lcol;
      __builtin_amdgcn_global_load_lds(
          (const __attribute__((address_space(1))) void*)gp,
          (__attribute__((address_space(3))) void*)(As + rbase * 32),
          16, 0, 0);
    }
    #pragma unroll
    for (int i = 0; i < TNB / 64; ++i) {
      const int rbase = i * 64 + wave * 16;
      const unsigned short* gp = Bw + (size_t)(rbase + lrow) * Kfull + k0 + lcol;
      __builtin_amdgcn_global_load_lds(
          (const __attribute__((address_space(1))) void*)gp,
          (__attribute__((address_space(3))) void*)(Bs + rbase * 32),
          16, 0, 0);
    }
    __syncthreads();

    bf16x8 af[4], bfr[NT];
    #pragma unroll
    for (int t = 0; t < 4; ++t)
      af[t]  = *reinterpret_cast<const bf16x8*>(As + (wm*64 + t*16 + fr)*32 + fq*8);
    #pragma unroll
    for (int t = 0; t < NT; ++t)
      bfr[t] = *reinterpret_cast<const bf16x8*>(Bs + (wn*WN + t*16 + fr)*32 + fq*8);
    #pragma unroll
    for (int mt = 0; mt < 4; ++mt)
      #pragma unroll
      for (int nt = 0; nt < NT; ++nt)
        acc[mt][nt] = __builtin_amdgcn_mfma_f32_16x16x32_bf16(
            af[mt], bfr[nt], acc[mt][nt], 0, 0, 0);
  }

  #pragma unroll
  for (int nt = 0; nt < NT; ++nt) {
    const int col = n0 + wn*WN + nt*16 + fr;
    #pragma unroll
    for (int mt = 0; mt < 4; ++mt)
      #pragma unroll
      for (int r = 0; r < 4; ++r) {
        const int row = m0 + wm*64 + mt*16 + fq*4 + r;
        Cw[(size_t)row * N + col] = acc[mt][nt][r];
      }
  }
}

// ---------------- split-K reduce: out = p0 + p1 + bias + res (bf16) --------
__global__ __launch_bounds__(256) void splitk_reduce(
    const float* __restrict__ p0, const float* __restrict__ p1,
    const float* __restrict__ bias, const unsigned short* __restrict__ res,
    float* __restrict__ out)
{
  const size_t i = ((size_t)blockIdx.x * 256 + threadIdx.x) * 4;
  float4 a = *reinterpret_cast<const float4*>(p0 + i);
  float4 b = *reinterpret_cast<const float4*>(p1 + i);
  float4 bv = *reinterpret_cast<const float4*>(bias + (i & (size_t)(C_ - 1)));
  const unsigned short* rp = res + i;
  float4 o;
  o.x = a.x + b.x + bv.x + bf2f(rp[0]);
  o.y = a.y + b.y + bv.y + bf2f(rp[1]);
  o.z = a.z + b.z + bv.z + bf2f(rp[2]);
  o.w = a.w + b.w + bv.w + bf2f(rp[3]);
  *reinterpret_cast<float4*>(out + i) = o;
}

// ---------------- V transpose: qkv V-part -> vt[bh][64 d][2048 t] bf16 -----
__global__ __launch_bounds__(256) void v_transpose(
    const unsigned short* __restrict__ qkv, unsigned short* __restrict__ vt)
{
  __shared__ __align__(16) unsigned short sT[64][72];
  const int st = blockIdx.x;        // s-tile of 64
  const int bh = blockIdx.y;
  const int b = bh >> 4, h = bh & 15;
  const int t = threadIdx.x;
  const int r = t >> 2, c0 = (t & 3) * 16;
  const unsigned short* src =
      qkv + (size_t)(b * T_ + st * 64 + r) * 3072 + 2048 + h * 64 + c0;
  *(u16x8*)&sT[r][c0]     = *(const u16x8*)src;
  *(u16x8*)&sT[r][c0 + 8] = *(const u16x8*)(src + 8);
  __syncthreads();
  const int d = t >> 2, sc = (t & 3) * 16;
  unsigned short v[16];
  #pragma unroll
  for (int j = 0; j < 16; ++j) v[j] = sT[sc + j][d];
  unsigned short* dst = vt + ((size_t)bh * 64 + d) * (size_t)T_ + st * 64 + sc;
  *(uint4*)dst       = *(uint4*)&v[0];
  *(uint4*)(dst + 8) = *(uint4*)&v[8];
}

// ---------------- MFMA flash attention v2 (S^T form) ----------------
__global__ __launch_bounds__(256, 4) void attn_mfma(
    const unsigned short* __restrict__ qkv,
    const unsigned short* __restrict__ vt,
    unsigned short* __restrict__ out)
{
  const int bh = blockIdx.x;
  const int qt = (int)(gridDim.y - 1) - (int)blockIdx.y;  // long blocks first
  const int b = bh >> 4, h = bh & 15;
  const int tid = threadIdx.x;
  const int w = tid >> 6;
  const int lane = tid & 63;
  const int l15 = lane & 15, fq = lane >> 4;
  const int t0 = qt * 64;
  const int q_row = t0 + w * 16 + l15;   // this lane's q column

  __shared__ __align__(16) unsigned short sK [64][72];
  __shared__ __align__(16) unsigned short sVt[64][72];
  __shared__ __align__(16) unsigned short sP [64][72];

  // Q fragment (dual-use A/B layout): Q[q_row][d = c*32 + fq*8 + j]
  bf16x8 aq[2];
  {
    const unsigned short* qp = qkv + (size_t)(b*T_ + q_row)*3072 + h*HS_ + fq*8;
    aq[0] = *(const bf16x8*)qp;
    aq[1] = *(const bf16x8*)(qp + 32);
  }

  floatx4 oacc[4] = {};   // [dt]; C/D: col d = dt*16+l15, row q-local = fq*4+r
  float m_s = -3.0e38f, l_s = 0.0f;
  const float c1 = 1.4426950408889634f / 32.0f;   // log2(e) * C^-0.5
  const int nks = qt + 1;

  for (int ks = 0; ks < nks; ++ks) {
    __syncthreads();   // everyone done reading sK/sVt from previous iter
    {   // stage K tile [s][d] and Vt tile [d][s]
      const int r = tid >> 2, c0 = (tid & 3) * 16;
      const unsigned short* kp =
          qkv + (size_t)(b*T_ + ks*64 + r)*3072 + C_ + h*HS_ + c0;
      u16x8 k0 = *(const u16x8*)kp, k1 = *(const u16x8*)(kp + 8);
      const unsigned short* vp =
          vt + ((size_t)bh*64 + r)*(size_t)T_ + ks*64 + c0;
      u16x8 v0 = *(const u16x8*)vp, v1 = *(const u16x8*)(vp + 8);
      *(u16x8*)&sK[r][c0]      = k0; *(u16x8*)&sK[r][c0 + 8]  = k1;
      *(u16x8*)&sVt[r][c0]     = v0; *(u16x8*)&sVt[r][c0 + 8] = v1;
    }
    __syncthreads();

    // S^T[st] = K-tile · Q^T : D[m = s-local = fq*4+r][n = q-local = l15]
    floatx4 stacc[4] = {};
    #pragma unroll
    for (int st = 0; st < 4; ++st) {
      bf16x8 k0 = *(const bf16x8*)&sK[st*16 + l15][fq*8];
      bf16x8 k1 = *(const bf16x8*)&sK[st*16 + l15][32 + fq*8];
      stacc[st] = __builtin_amdgcn_mfma_f32_16x16x32_bf16(k0, aq[0], stacc[st], 0, 0, 0);
      stacc[st] = __builtin_amdgcn_mfma_f32_16x16x32_bf16(k1, aq[1], stacc[st], 0, 0, 0);
    }

    if (ks == qt) {   // diagonal tile: mask s > q
      #pragma unroll
      for (int st = 0; st < 4; ++st)
        #pragma unroll
        for (int r = 0; r < 4; ++r) {
          const int s = ks*64 + st*16 + fq*4 + r;
          if (s > q_row) stacc[st][r] = -3.0e38f;
        }
    }

    // online softmax over s for this lane's q: in-lane 16 + 2 shfl_xor
    float mx = -3.0e38f;
    #pragma unroll
    for (int st = 0; st < 4; ++st)
      #pragma unroll
      for (int r = 0; r < 4; ++r) mx = fmaxf(mx, stacc[st][r]);
    mx = fmaxf(mx, __shfl_xor(mx, 16, 64));
    mx = fmaxf(mx, __shfl_xor(mx, 32, 64));
    const float mnew = fmaxf(m_s, mx);
    const float alpha = exp2f((m_s - mnew) * c1);
    m_s = mnew;

    float sum = 0.0f;
    #pragma unroll
    for (int st = 0; st < 4; ++st) {
      unsigned pu[4];
      #pragma unroll
      for (int r = 0; r < 4; ++r) {
        const float p = exp2f((stacc[st][r] - mnew) * c1);
        sum += p;
        union { float f; unsigned u; } cv; cv.f = p;
        pu[r] = cv.u + 0x8000u;              // round-half-up to bf16
      }
      const unsigned lo = __builtin_amdgcn_perm(pu[1], pu[0], 0x07060302u);
      const unsigned hi = __builtin_amdgcn_perm(pu[3], pu[2], 0x07060302u);
      const unsigned long long pk = ((unsigned long long)hi << 32) | lo;
      // P[q][s]: row = wave-private q, col = 4 consecutive s
      *(unsigned long long*)&sP[w*16 + l15][st*16 + fq*4] = pk;
    }
    sum += __shfl_xor(sum, 16, 64);
    sum += __shfl_xor(sum, 32, 64);
    l_s = l_s * alpha + sum;

    // rescale O rows (alpha lives at lane l15 == q-local; O row = fq*4+r)
    #pragma unroll
    for (int r = 0; r < 4; ++r) {
      const float ar = __shfl(alpha, fq*4 + r, 64);
      #pragma unroll
      for (int dt = 0; dt < 4; ++dt) oacc[dt][r] *= ar;
    }

    // PV: O[q][d] += P[q][s] · V[s][d]   (sP rows are wave-private: no barrier)
    #pragma unroll
    for (int c = 0; c < 2; ++c) {
      bf16x8 ap = *(const bf16x8*)&sP[w*16 + l15][c*32 + fq*8];
      #pragma unroll
      for (int dt = 0; dt < 4; ++dt) {
        bf16x8 bv = *(const bf16x8*)&sVt[dt*16 + l15][c*32 + fq*8];
        oacc[dt] = __builtin_amdgcn_mfma_f32_16x16x32_bf16(ap, bv, oacc[dt], 0, 0, 0);
      }
    }
  }

  // epilogue: O /= l, write bf16 [token][h*64 + d]
  #pragma unroll
  for (int r = 0; r < 4; ++r) {
    const float il = 1.0f / __shfl(l_s, fq*4 + r, 64);
    const int q = t0 + w*16 + fq*4 + r;
    #pragma unroll
    for (int dt = 0; dt < 4; ++dt)
      out[(size_t)(b*T_ + q)*C_ + h*HS_ + dt*16 + l15] = f2bf(oacc[dt][r] * il);
  }
}

extern "C" void kernel_launch(void* const* d_in, const int* in_sizes, int n_in,
                              void* d_out, int out_size, void* d_ws, size_t ws_size,
                              hipStream_t stream)
{
  const float* x   = (const float*)d_in[0];
  const float* Wq  = (const float*)d_in[1];
  const float* Wk  = (const float*)d_in[2];
  const float* Wv  = (const float*)d_in[3];
  const float* Wo  = (const float*)d_in[4];
  const float* bo  = (const float*)d_in[5];
  const float* W1  = (const float*)d_in[6];
  const float* b1  = (const float*)d_in[7];
  const float* W2  = (const float*)d_in[8];
  const float* b2  = (const float*)d_in[9];
  const float* g1  = (const float*)d_in[10];
  const float* be1 = (const float*)d_in[11];
  const float* g2  = (const float*)d_in[12];
  const float* be2 = (const float*)d_in[13];
  float* out = (float*)d_out;

  // Workspace (88 MB peak, liveness-based reuse):
  char* ws = (char*)d_ws;
  unsigned short* BtQKV = (unsigned short*)(ws + (size_t) 0*MB);  // 6MB
  unsigned short* BtWo  = (unsigned short*)(ws + (size_t) 6*MB);  // 2MB
  unsigned short* BtW1  = (unsigned short*)(ws + (size_t) 8*MB);  // 8MB
  unsigned short* BtW2  = (unsigned short*)(ws + (size_t)16*MB);  // 8MB
  unsigned short* lnb   = (unsigned short*)(ws + (size_t)24*MB);  // 8MB
  unsigned short* qkvb  = (unsigned short*)(ws + (size_t)32*MB);  // [4096][3072] 24MB
  unsigned short* vtb   = (unsigned short*)(ws + (size_t)56*MB);  // [32][64][2048] 8MB
  unsigned short* attnb = (unsigned short*)(ws + (size_t)64*MB);  // 8MB
  float*          x2    = (float*)         (ws + (size_t)32*MB);  // 16MB (qkv dead)
  unsigned short* hb    = (unsigned short*)(ws + (size_t)32*MB);  // 32MB (x2,vt dead)
  // split-K partials for W2. NOT contiguous! p0 over dead weight bufs
  // (BtQKV/BtWo/BtW1, 0-16MB); p1 over dead attnb + tail (72-88MB).
  // BtW2 (16-24MB) stays live as the B operand — must not be touched.
  float*          p0    = (float*)         (ws + (size_t) 0*MB);  // 16MB
  float*          p1    = (float*)         (ws + (size_t)72*MB);  // 16MB

  dim3 blk(256);

  transpose_cast<<<dim3(HS_/32, C_/32, H_), blk, 0, stream>>>(Wq, BtQKV,               C_, HS_);
  transpose_cast<<<dim3(HS_/32, C_/32, H_), blk, 0, stream>>>(Wk, BtQKV + 1024*1024,   C_, HS_);
  transpose_cast<<<dim3(HS_/32, C_/32, H_), blk, 0, stream>>>(Wv, BtQKV + 2*1024*1024, C_, HS_);
  transpose_cast<<<dim3(C_/32,  C_/32, 1),  blk, 0, stream>>>(Wo, BtWo, C_, C_);
  transpose_cast<<<dim3(4*C_/32,C_/32, 1),  blk, 0, stream>>>(W1, BtW1, C_, 4*C_);
  transpose_cast<<<dim3(C_/32,4*C_/32, 1),  blk, 0, stream>>>(W2, BtW2, 4*C_, C_);

  ln_kernel<<<dim3(N_ROWS), blk, 0, stream>>>(x, g1, be1, lnb);

  // Fused QKV GEMM -> bf16 [4096][3072]   (768 blocks)
  gemm_bf16<128,true,false,false,false><<<dim3(N_ROWS/128, 3072/128), blk, 0, stream>>>(
      lnb, BtQKV, nullptr, nullptr, qkvb, N_ROWS, 3072, C_);

  // V transpose -> vt[bh][d][t]
  v_transpose<<<dim3(T_/64, B_*H_), blk, 0, stream>>>(qkvb, vtb);

  // MFMA flash attention -> bf16 attnb  (32 bh x 32 qt = 1024 blocks)
  attn_mfma<<<dim3(B_*H_, T_/64), blk, 0, stream>>>(qkvb, vtb, attnb);

  // Wo GEMM + bias + residual(ln1) -> fp32 x2   (TN=64: 512 blocks)
  gemm_bf16<64,false,false,true,true><<<dim3(N_ROWS/128, C_/64), blk, 0, stream>>>(
      attnb, BtWo, bo, lnb, x2, N_ROWS, C_, C_);

  // LN2
  ln_kernel<<<dim3(N_ROWS), blk, 0, stream>>>(x2, g2, be2, lnb);

  // W1 GEMM + bias + ReLU -> bf16 hb   (1024 blocks)
  gemm_bf16<128,true,true,true,false><<<dim3(N_ROWS/128, 4*C_/128), blk, 0, stream>>>(
      lnb, BtW1, b1, nullptr, hb, N_ROWS, 4*C_, C_);

  // W2 GEMM split-K=2 -> fp32 partials   (32 x 16 x 2 = 1024 blocks)
  gemm_splitk<64><<<dim3(N_ROWS/128, C_/64, 2), blk, 0, stream>>>(
      hb, BtW2, p0, p1, N_ROWS, C_, 4*C_);

  // reduce: out = p0 + p1 + b2 + residual(ln2)
  splitk_reduce<<<dim3((N_ROWS * C_) / (256 * 4)), blk, 0, stream>>>(
      p0, p1, b2, lnb, out);
}